// Round 1
// baseline (1224.949 us; speedup 1.0000x reference)
//
#include <hip/hip_runtime.h>
#include <hip/hip_bf16.h>

#define N_NODES 80000
#define N_EDGES 1280000
#define E_TOT   (N_EDGES + N_NODES)   // + self loops
#define N_GRAPHS 256
#define NEG_SLOPE 0.2f

// ---------------------------------------------------------------------------
// CSR build (by dst). Self-loop occupies slot 0 of every node's segment.
// ---------------------------------------------------------------------------
__global__ void k_init_counts(int* __restrict__ counts, int n) {
    int i = blockIdx.x * blockDim.x + threadIdx.x;
    if (i < n) counts[i] = 1;   // self loop
}

__global__ void k_hist(const int* __restrict__ dst, int* __restrict__ counts, int e) {
    int i = blockIdx.x * blockDim.x + threadIdx.x;
    if (i < e) atomicAdd(&counts[dst[i]], 1);
}

// single-block exclusive scan, 1024 threads, ping-pong LDS
__global__ void k_scan(const int* __restrict__ counts, int* __restrict__ row_ptr, int n) {
    __shared__ int sa[1024], sb[1024];
    int tid = threadIdx.x;
    int offset = 0;
    for (int base = 0; base < n; base += 1024) {
        int v = (base + tid < n) ? counts[base + tid] : 0;
        sa[tid] = v;
        __syncthreads();
        int* cur = sa; int* nxt = sb;
        #pragma unroll
        for (int d = 1; d < 1024; d <<= 1) {
            int t = cur[tid];
            if (tid >= d) t += cur[tid - d];
            nxt[tid] = t;
            __syncthreads();
            int* tmp = cur; cur = nxt; nxt = tmp;
        }
        int incl = cur[tid];
        if (base + tid < n) row_ptr[base + tid] = offset + incl - v;
        offset += cur[1023];
        __syncthreads();
    }
    if (tid == 0) row_ptr[n] = offset;
}

__global__ void k_scatter_init(const int* __restrict__ row_ptr, int* __restrict__ srcs,
                               int* __restrict__ fill, int n) {
    int i = blockIdx.x * blockDim.x + threadIdx.x;
    if (i < n) {
        srcs[row_ptr[i]] = i;   // self loop at slot 0
        fill[i] = 1;
    }
}

__global__ void k_scatter(const int* __restrict__ src, const int* __restrict__ dst,
                          const int* __restrict__ row_ptr, int* __restrict__ fill,
                          int* __restrict__ srcs, int e) {
    int i = blockIdx.x * blockDim.x + threadIdx.x;
    if (i < e) {
        int d = dst[i];
        int pos = row_ptr[d] + atomicAdd(&fill[d], 1);
        srcs[pos] = src[i];
    }
}

// ---------------------------------------------------------------------------
// Linear layers: thread-per-node, W in LDS, fused a_src/a_dst dot products.
// Layer inputs (except layer 1's x) get ReLU applied on load.
// ---------------------------------------------------------------------------
__global__ void k_lin1(const float* __restrict__ x, const float* __restrict__ W,
                       const float* __restrict__ asrc, const float* __restrict__ adst,
                       float* __restrict__ h, float* __restrict__ als, float* __restrict__ ald,
                       int n) {
    __shared__ float Wl[9 * 135];
    __shared__ float As[135], Ad[135];
    for (int i = threadIdx.x; i < 9 * 135; i += blockDim.x) Wl[i] = W[i];
    for (int i = threadIdx.x; i < 135; i += blockDim.x) { As[i] = asrc[i]; Ad[i] = adst[i]; }
    __syncthreads();
    int node = blockIdx.x * blockDim.x + threadIdx.x;
    if (node >= n) return;
    float r[9];
    #pragma unroll
    for (int k = 0; k < 9; ++k) r[k] = x[(long)node * 9 + k];
    float as_[3] = {0.f, 0.f, 0.f}, ad_[3] = {0.f, 0.f, 0.f};
    for (int head = 0; head < 3; ++head) {
        for (int c = 0; c < 45; ++c) {
            int col = head * 45 + c;
            float s = 0.f;
            #pragma unroll
            for (int k = 0; k < 9; ++k) s += r[k] * Wl[k * 135 + col];
            h[(long)node * 135 + col] = s;
            as_[head] += s * As[col];
            ad_[head] += s * Ad[col];
        }
    }
    #pragma unroll
    for (int hh = 0; hh < 3; ++hh) { als[node * 3 + hh] = as_[hh]; ald[node * 3 + hh] = ad_[hh]; }
}

__global__ void k_lin2(const float* __restrict__ in, const float* __restrict__ W,
                       const float* __restrict__ asrc, const float* __restrict__ adst,
                       float* __restrict__ h, float* __restrict__ als, float* __restrict__ ald,
                       int n) {
    __shared__ float Wl[135 * 54];
    __shared__ float As[54], Ad[54];
    for (int i = threadIdx.x; i < 135 * 54; i += blockDim.x) Wl[i] = W[i];
    for (int i = threadIdx.x; i < 54; i += blockDim.x) { As[i] = asrc[i]; Ad[i] = adst[i]; }
    __syncthreads();
    int node = blockIdx.x * blockDim.x + threadIdx.x;
    if (node >= n) return;
    float acc[54];
    #pragma unroll
    for (int c = 0; c < 54; ++c) acc[c] = 0.f;
    for (int k = 0; k < 135; ++k) {
        float xk = in[(long)node * 135 + k];
        xk = fmaxf(xk, 0.f);   // ReLU from previous layer
        #pragma unroll
        for (int c = 0; c < 54; ++c) acc[c] += xk * Wl[k * 54 + c];
    }
    float as_[3] = {0.f, 0.f, 0.f}, ad_[3] = {0.f, 0.f, 0.f};
    #pragma unroll
    for (int c = 0; c < 54; ++c) {
        h[(long)node * 54 + c] = acc[c];
        as_[c / 18] += acc[c] * As[c];
        ad_[c / 18] += acc[c] * Ad[c];
    }
    #pragma unroll
    for (int hh = 0; hh < 3; ++hh) { als[node * 3 + hh] = as_[hh]; ald[node * 3 + hh] = ad_[hh]; }
}

__global__ void k_lin3(const float* __restrict__ in, const float* __restrict__ W,
                       const float* __restrict__ asrc, const float* __restrict__ adst,
                       float* __restrict__ h, float* __restrict__ als, float* __restrict__ ald,
                       int n) {
    __shared__ float Wl[54 * 4];
    __shared__ float As[4], Ad[4];
    for (int i = threadIdx.x; i < 54 * 4; i += blockDim.x) Wl[i] = W[i];
    for (int i = threadIdx.x; i < 4; i += blockDim.x) { As[i] = asrc[i]; Ad[i] = adst[i]; }
    __syncthreads();
    int node = blockIdx.x * blockDim.x + threadIdx.x;
    if (node >= n) return;
    float acc[4] = {0.f, 0.f, 0.f, 0.f};
    for (int k = 0; k < 54; ++k) {
        float xk = in[(long)node * 54 + k];
        xk = fmaxf(xk, 0.f);   // ReLU from previous layer
        #pragma unroll
        for (int c = 0; c < 4; ++c) acc[c] += xk * Wl[k * 4 + c];
    }
    float as_ = 0.f, ad_ = 0.f;
    #pragma unroll
    for (int c = 0; c < 4; ++c) {
        h[(long)node * 4 + c] = acc[c];
        as_ += acc[c] * As[c];
        ad_ += acc[c] * Ad[c];
    }
    als[node] = as_;
    ald[node] = ad_;
}

// ---------------------------------------------------------------------------
// Aggregation: one wave per node. Pass A: segment max. Pass B: sum of exp.
// Pass C: channel-parallel weighted gather-accumulate (coalesced h[src] rows).
// Writes out = segment_sum(h[src]*alpha) + bias.
// ---------------------------------------------------------------------------
template <int H, int C>
__global__ void k_agg(const int* __restrict__ row_ptr, const int* __restrict__ srcs,
                      const float* __restrict__ h, const float* __restrict__ als,
                      const float* __restrict__ ald, const float* __restrict__ bias,
                      float* __restrict__ out, int n) {
    constexpr int CT = H * C;
    constexpr int CPL = (CT + 63) / 64;
    int wid = threadIdx.x >> 6;
    int lane = threadIdx.x & 63;
    int node = blockIdx.x * (blockDim.x >> 6) + wid;
    if (node >= n) return;
    int beg = row_ptr[node], end = row_ptr[node + 1];

    float aldv[H];
    #pragma unroll
    for (int hh = 0; hh < H; ++hh) aldv[hh] = ald[node * H + hh];

    // Pass A: per-head max over incoming edges
    float m[H];
    #pragma unroll
    for (int hh = 0; hh < H; ++hh) m[hh] = -1e30f;
    for (int i = beg + lane; i < end; i += 64) {
        int s = srcs[i];
        #pragma unroll
        for (int hh = 0; hh < H; ++hh) {
            float a = als[s * H + hh] + aldv[hh];
            a = a > 0.f ? a : NEG_SLOPE * a;
            m[hh] = fmaxf(m[hh], a);
        }
    }
    #pragma unroll
    for (int hh = 0; hh < H; ++hh) {
        for (int off = 32; off; off >>= 1)
            m[hh] = fmaxf(m[hh], __shfl_xor(m[hh], off, 64));
    }

    // Pass B: per-head sum of exp
    float ss[H];
    #pragma unroll
    for (int hh = 0; hh < H; ++hh) ss[hh] = 0.f;
    for (int i = beg + lane; i < end; i += 64) {
        int s = srcs[i];
        #pragma unroll
        for (int hh = 0; hh < H; ++hh) {
            float a = als[s * H + hh] + aldv[hh];
            a = a > 0.f ? a : NEG_SLOPE * a;
            ss[hh] += expf(a - m[hh]);
        }
    }
    #pragma unroll
    for (int hh = 0; hh < H; ++hh) {
        for (int off = 32; off; off >>= 1)
            ss[hh] += __shfl_xor(ss[hh], off, 64);
    }
    float inv[H];
    #pragma unroll
    for (int hh = 0; hh < H; ++hh) inv[hh] = 1.f / (ss[hh] + 1e-16f);

    // Pass C: channel-parallel accumulation; all lanes walk every edge,
    // weight computed redundantly (broadcast loads), h[src] reads coalesced.
    float acc[CPL];
    int headof[CPL];
    #pragma unroll
    for (int j = 0; j < CPL; ++j) {
        acc[j] = 0.f;
        int ch = lane + j * 64;
        headof[j] = (ch < CT) ? (ch / C) : 0;
    }
    for (int i = beg; i < end; ++i) {
        int s = srcs[i];
        float w[H];
        #pragma unroll
        for (int hh = 0; hh < H; ++hh) {
            float a = als[s * H + hh] + aldv[hh];
            a = a > 0.f ? a : NEG_SLOPE * a;
            w[hh] = expf(a - m[hh]) * inv[hh];
        }
        const float* hr = h + (long)s * CT;
        #pragma unroll
        for (int j = 0; j < CPL; ++j) {
            int ch = lane + j * 64;
            if (ch < CT) acc[j] += hr[ch] * w[headof[j]];
        }
    }
    #pragma unroll
    for (int j = 0; j < CPL; ++j) {
        int ch = lane + j * 64;
        if (ch < CT) out[(long)node * CT + ch] = acc[j] + bias[ch];
    }
}

// ---------------------------------------------------------------------------
// Global max pool (monotone-uint atomicMax) + log_softmax
// ---------------------------------------------------------------------------
__device__ __forceinline__ unsigned f2mono(float f) {
    unsigned u = __float_as_uint(f);
    return u ^ ((u >> 31) ? 0xFFFFFFFFu : 0x80000000u);
}
__device__ __forceinline__ float mono2f(unsigned u) {
    u = (u & 0x80000000u) ? (u ^ 0x80000000u) : ~u;
    return __uint_as_float(u);
}

__global__ void k_pool_init(unsigned* __restrict__ genc) {
    int i = blockIdx.x * blockDim.x + threadIdx.x;
    if (i < N_GRAPHS * 4) genc[i] = f2mono(-1e9f);
}

__global__ void k_pool(const float* __restrict__ h3, const int* __restrict__ batch,
                       unsigned* __restrict__ genc, int n) {
    int i = blockIdx.x * blockDim.x + threadIdx.x;
    if (i >= n) return;
    int g = batch[i];
    #pragma unroll
    for (int c = 0; c < 4; ++c) {
        atomicMax(&genc[g * 4 + c], f2mono(h3[(long)i * 4 + c]));
    }
}

__global__ void k_final(const unsigned* __restrict__ genc, float* __restrict__ out) {
    int g = threadIdx.x;   // 256 threads, one per graph
    float v[4];
    #pragma unroll
    for (int c = 0; c < 4; ++c) v[c] = mono2f(genc[g * 4 + c]);
    float mx = fmaxf(fmaxf(v[0], v[1]), fmaxf(v[2], v[3]));
    float s = 0.f;
    #pragma unroll
    for (int c = 0; c < 4; ++c) s += expf(v[c] - mx);
    float l = mx + logf(s);
    #pragma unroll
    for (int c = 0; c < 4; ++c) out[g * 4 + c] = v[c] - l;
}

// ---------------------------------------------------------------------------
extern "C" void kernel_launch(void* const* d_in, const int* in_sizes, int n_in,
                              void* d_out, int out_size, void* d_ws, size_t ws_size,
                              hipStream_t stream) {
    const float* x     = (const float*)d_in[0];
    const int*   ei    = (const int*)d_in[1];     // [2, E] flat
    const int*   batch = (const int*)d_in[2];
    const float* W1    = (const float*)d_in[3];
    const float* as1   = (const float*)d_in[4];
    const float* ad1   = (const float*)d_in[5];
    const float* b1    = (const float*)d_in[6];
    const float* W2    = (const float*)d_in[7];
    const float* as2   = (const float*)d_in[8];
    const float* ad2   = (const float*)d_in[9];
    const float* b2    = (const float*)d_in[10];
    const float* W3    = (const float*)d_in[11];
    const float* as3   = (const float*)d_in[12];
    const float* ad3   = (const float*)d_in[13];
    const float* b3    = (const float*)d_in[14];
    float* out = (float*)d_out;

    const int* src = ei;
    const int* dst = ei + N_EDGES;

    // workspace layout
    char* base = (char*)d_ws;
    size_t off = 0;
    auto alloc = [&](size_t bytes) -> char* {
        char* p = base + off;
        off = (off + bytes + 255) & ~(size_t)255;
        return p;
    };
    int*      counts  = (int*)alloc((size_t)N_NODES * 4);
    int*      fill    = (int*)alloc((size_t)N_NODES * 4);
    int*      row_ptr = (int*)alloc((size_t)(N_NODES + 1) * 4);
    int*      srcs    = (int*)alloc((size_t)E_TOT * 4);
    float*    als     = (float*)alloc((size_t)N_NODES * 3 * 4);
    float*    ald     = (float*)alloc((size_t)N_NODES * 3 * 4);
    float*    bufA    = (float*)alloc((size_t)N_NODES * 135 * 4);
    float*    bufB    = (float*)alloc((size_t)N_NODES * 135 * 4);
    unsigned* genc    = (unsigned*)alloc((size_t)N_GRAPHS * 4 * 4);
    if (off > ws_size) return;   // workspace too small; bail (output stays poisoned)

    const int TB = 256;
    const int nb_n = (N_NODES + TB - 1) / TB;
    const int nb_e = (N_EDGES + TB - 1) / TB;
    const int nb_w = (N_NODES + 3) / 4;   // 4 waves (nodes) per 256-thread block

    // --- CSR build ---
    k_init_counts<<<nb_n, TB, 0, stream>>>(counts, N_NODES);
    k_hist<<<nb_e, TB, 0, stream>>>(dst, counts, N_EDGES);
    k_scan<<<1, 1024, 0, stream>>>(counts, row_ptr, N_NODES);
    k_scatter_init<<<nb_n, TB, 0, stream>>>(row_ptr, srcs, fill, N_NODES);
    k_scatter<<<nb_e, TB, 0, stream>>>(src, dst, row_ptr, fill, srcs, N_EDGES);

    // --- layer 1: 9 -> 3x45 ---
    k_lin1<<<nb_n, TB, 0, stream>>>(x, W1, as1, ad1, bufA, als, ald, N_NODES);
    k_agg<3, 45><<<nb_w, TB, 0, stream>>>(row_ptr, srcs, bufA, als, ald, b1, bufB, N_NODES);

    // --- layer 2: 135 -> 3x18 (ReLU on load) ---
    k_lin2<<<nb_n, TB, 0, stream>>>(bufB, W2, as2, ad2, bufA, als, ald, N_NODES);
    k_agg<3, 18><<<nb_w, TB, 0, stream>>>(row_ptr, srcs, bufA, als, ald, b2, bufB, N_NODES);

    // --- layer 3: 54 -> 1x4 (ReLU on load) ---
    k_lin3<<<nb_n, TB, 0, stream>>>(bufB, W3, as3, ad3, bufA, als, ald, N_NODES);
    k_agg<1, 4><<<nb_w, TB, 0, stream>>>(row_ptr, srcs, bufA, als, ald, b3, bufB, N_NODES);

    // --- pool + log_softmax ---
    k_pool_init<<<(N_GRAPHS * 4 + TB - 1) / TB, TB, 0, stream>>>(genc);
    k_pool<<<nb_n, TB, 0, stream>>>(bufB, batch, genc, N_NODES);
    k_final<<<1, N_GRAPHS, 0, stream>>>(genc, out);
}

// Round 3
// 874.315 us; speedup vs baseline: 1.4010x; 1.4010x over previous
//
#include <hip/hip_runtime.h>
#include <hip/hip_bf16.h>

#define N_NODES 80000
#define N_EDGES 1280000
#define E_TOT   (N_EDGES + N_NODES)   // + self loops
#define N_GRAPHS 256
#define NEG_SLOPE 0.2f

// leaky_relu(a) = max(a, 0.2*a)  (valid since 0<slope<1)
__device__ __forceinline__ float leaky(float a) { return fmaxf(a, NEG_SLOPE * a); }

// pick arr[h] with runtime h from a static-unrolled register array (no scratch)
template <int H>
__device__ __forceinline__ float pick(const float (&arr)[H], int h) {
    float r = arr[0];
    #pragma unroll
    for (int j = 1; j < H; ++j) r = (h == j) ? arr[j] : r;
    return r;
}

// ---------------------------------------------------------------------------
// CSR build (by dst). Self-loops appended as virtual edges i in [E, E+N).
// ---------------------------------------------------------------------------
__global__ void k_hist(const int* __restrict__ dst, int* __restrict__ counts) {
    int i = blockIdx.x * blockDim.x + threadIdx.x;
    if (i >= E_TOT) return;
    int d = (i < N_EDGES) ? dst[i] : (i - N_EDGES);
    atomicAdd(&counts[d], 1);
}

#define SCAN_B 256
__global__ void k_scan_block(const int* __restrict__ counts, int* __restrict__ rp,
                             int* __restrict__ bsum, int n) {
    __shared__ int sa[SCAN_B], sb[SCAN_B];
    int tid = threadIdx.x;
    int gi = blockIdx.x * SCAN_B + tid;
    int v = (gi < n) ? counts[gi] : 0;
    sa[tid] = v;
    __syncthreads();
    int* cur = sa; int* nxt = sb;
    #pragma unroll
    for (int d = 1; d < SCAN_B; d <<= 1) {
        int t = cur[tid];
        if (tid >= d) t += cur[tid - d];
        nxt[tid] = t;
        __syncthreads();
        int* tmp = cur; cur = nxt; nxt = tmp;
    }
    if (gi < n) rp[gi] = cur[tid] - v;            // block-local exclusive
    if (tid == SCAN_B - 1) bsum[blockIdx.x] = cur[tid];
}

__global__ void k_scan_tops(const int* __restrict__ bsum, int* __restrict__ boff, int nb) {
    __shared__ int sa[512], sb[512];
    int tid = threadIdx.x;
    int v = (tid < nb) ? bsum[tid] : 0;
    sa[tid] = v;
    __syncthreads();
    int* cur = sa; int* nxt = sb;
    #pragma unroll
    for (int d = 1; d < 512; d <<= 1) {
        int t = cur[tid];
        if (tid >= d) t += cur[tid - d];
        nxt[tid] = t;
        __syncthreads();
        int* tmp = cur; cur = nxt; nxt = tmp;
    }
    if (tid < nb) boff[tid] = cur[tid] - v;
}

__global__ void k_scan_add(int* __restrict__ rp, const int* __restrict__ boff, int n) {
    int gi = blockIdx.x * blockDim.x + threadIdx.x;
    if (gi < n) rp[gi] += boff[blockIdx.x];
    if (gi == 0) rp[n] = E_TOT;
}

__global__ void k_scatter(const int* __restrict__ src, const int* __restrict__ dst,
                          const int* __restrict__ rp, int* __restrict__ fill,
                          int* __restrict__ srcs) {
    int i = blockIdx.x * blockDim.x + threadIdx.x;
    if (i >= E_TOT) return;
    int s, d;
    if (i < N_EDGES) { s = src[i]; d = dst[i]; }
    else             { s = i - N_EDGES; d = s; }
    int pos = rp[d] + atomicAdd(&fill[d], 1);
    srcs[pos] = s;
}

// ---------------------------------------------------------------------------
// Layer 1 pre-pass: als1/ald1 directly from x via projected 3x9 matrices
// ps[h][k] = sum_c W1[k, h*45+c] * a_src[h,c]   (h1 never materialized!)
// ---------------------------------------------------------------------------
__global__ void k_pre1(const float* __restrict__ x, const float* __restrict__ W1,
                       const float* __restrict__ as1, const float* __restrict__ ad1,
                       float* __restrict__ als, float* __restrict__ ald, int n) {
    __shared__ float ps[27], pd[27];
    int t = threadIdx.x;
    if (t < 27) {
        int h = t / 9, k = t % 9;
        float s = 0.f, d = 0.f;
        for (int c = 0; c < 45; ++c) {
            float w = W1[k * 135 + h * 45 + c];
            s += w * as1[h * 45 + c];
            d += w * ad1[h * 45 + c];
        }
        ps[t] = s; pd[t] = d;
    }
    __syncthreads();
    int node = blockIdx.x * blockDim.x + t;
    if (node >= n) return;
    float xr[9];
    #pragma unroll
    for (int k = 0; k < 9; ++k) xr[k] = x[node * 9 + k];
    #pragma unroll
    for (int h = 0; h < 3; ++h) {
        float s = 0.f, d = 0.f;
        #pragma unroll
        for (int k = 0; k < 9; ++k) { s += xr[k] * ps[h * 9 + k]; d += xr[k] * pd[h * 9 + k]; }
        als[node * 3 + h] = s;
        ald[node * 3 + h] = d;
    }
}

// ---------------------------------------------------------------------------
// Layer 1 aggregation over x (factorized): aggx[n, h*9+k] = sum_e w_h(e) x[src,k]
// One wave per node. Online max+sum, then channel-parallel pass with
// 2 edges per iteration (lanes split 2 x 32, 27 active channels each).
// ---------------------------------------------------------------------------
__global__ void k_agg1x(const int* __restrict__ rp, const int* __restrict__ srcs,
                        const float* __restrict__ x, const float* __restrict__ als,
                        const float* __restrict__ ald, float* __restrict__ aggx, int n) {
    int wid = threadIdx.x >> 6, lane = threadIdx.x & 63;
    int node = blockIdx.x * (blockDim.x >> 6) + wid;
    if (node >= n) return;
    int beg = rp[node], end = rp[node + 1];

    float aldv[3];
    #pragma unroll
    for (int h = 0; h < 3; ++h) aldv[h] = ald[node * 3 + h];

    // online per-head max + sum-of-exp
    float m[3], ss[3];
    #pragma unroll
    for (int h = 0; h < 3; ++h) { m[h] = -1e30f; ss[h] = 0.f; }
    for (int i = beg + lane; i < end; i += 64) {
        int s = srcs[i];
        #pragma unroll
        for (int h = 0; h < 3; ++h) {
            float a = leaky(als[s * 3 + h] + aldv[h]);
            float nm = fmaxf(m[h], a);
            ss[h] = ss[h] * __expf(m[h] - nm) + __expf(a - nm);
            m[h] = nm;
        }
    }
    #pragma unroll
    for (int h = 0; h < 3; ++h) {
        for (int off = 32; off; off >>= 1) {
            float om = __shfl_xor(m[h], off, 64);
            float os = __shfl_xor(ss[h], off, 64);
            float nm = fmaxf(m[h], om);
            ss[h] = ss[h] * __expf(m[h] - nm) + os * __expf(om - nm);
            m[h] = nm;
        }
    }
    float inv[3];
    #pragma unroll
    for (int h = 0; h < 3; ++h) inv[h] = 1.f / (ss[h] + 1e-16f);

    // channel-parallel: li in [0,27): (h, k); two edge slots (es = lane>>5)
    int es = lane >> 5, li = lane & 31;
    bool act = li < 27;
    int hh = act ? li / 9 : 0;
    int kk = act ? li % 9 : 0;
    float aldh = pick(aldv, hh), mh = pick(m, hh), invh = pick(inv, hh);

    float acc = 0.f;
    for (int i = beg + es; i < end; i += 2) {
        int s = srcs[i];
        float a = leaky(als[s * 3 + hh] + aldh);
        float w = __expf(a - mh) * invh;
        if (act) acc += x[s * 9 + kk] * w;
    }
    acc += __shfl_xor(acc, 32, 64);
    if (lane < 27) aggx[node * 27 + lane] = acc;
}

// ---------------------------------------------------------------------------
// Fused: out1 = aggx @ W1 + b1 -> ReLU -> h2 = out1 @ W2 ; als2/ald2 dots.
// Thread per node. W reads are wave-uniform -> scalar loads via L2/K$.
// ---------------------------------------------------------------------------
__global__ void k_lin2f(const float* __restrict__ aggx, const float* __restrict__ W1,
                        const float* __restrict__ b1, const float* __restrict__ W2,
                        const float* __restrict__ as2, const float* __restrict__ ad2,
                        float* __restrict__ h2, float* __restrict__ als,
                        float* __restrict__ ald, int n) {
    int node = blockIdx.x * blockDim.x + threadIdx.x;
    if (node >= n) return;
    float ax[27];
    #pragma unroll
    for (int j = 0; j < 27; ++j) ax[j] = aggx[node * 27 + j];
    float acc[54];
    #pragma unroll
    for (int c = 0; c < 54; ++c) acc[c] = 0.f;
    #pragma unroll
    for (int h = 0; h < 3; ++h) {          // must be unrolled: ax[] static idx
        #pragma unroll 1
        for (int c0 = 0; c0 < 45; ++c0) {
            int col = h * 45 + c0;
            float t = b1[col];
            #pragma unroll
            for (int k = 0; k < 9; ++k) t += ax[h * 9 + k] * W1[k * 135 + col];
            t = fmaxf(t, 0.f);             // ReLU between layers
            #pragma unroll
            for (int cc = 0; cc < 54; ++cc) acc[cc] += t * W2[col * 54 + cc];
        }
    }
    float as_[3] = {0.f, 0.f, 0.f}, ad_[3] = {0.f, 0.f, 0.f};
    #pragma unroll
    for (int c = 0; c < 54; ++c) {
        h2[node * 54 + c] = acc[c];
        as_[c / 18] += acc[c] * as2[c];
        ad_[c / 18] += acc[c] * ad2[c];
    }
    #pragma unroll
    for (int h = 0; h < 3; ++h) { als[node * 3 + h] = as_[h]; ald[node * 3 + h] = ad_[h]; }
}

// ---------------------------------------------------------------------------
// Generic aggregation (layer 2): gather h rows, channel-parallel pass C.
// ---------------------------------------------------------------------------
template <int H, int C>
__global__ void k_agg(const int* __restrict__ rp, const int* __restrict__ srcs,
                      const float* __restrict__ h, const float* __restrict__ als,
                      const float* __restrict__ ald, const float* __restrict__ bias,
                      float* __restrict__ out, int n) {
    constexpr int CT = H * C;
    int wid = threadIdx.x >> 6, lane = threadIdx.x & 63;
    int node = blockIdx.x * (blockDim.x >> 6) + wid;
    if (node >= n) return;
    int beg = rp[node], end = rp[node + 1];

    float aldv[H];
    #pragma unroll
    for (int hh = 0; hh < H; ++hh) aldv[hh] = ald[node * H + hh];

    float m[H], ss[H];
    #pragma unroll
    for (int hh = 0; hh < H; ++hh) { m[hh] = -1e30f; ss[hh] = 0.f; }
    for (int i = beg + lane; i < end; i += 64) {
        int s = srcs[i];
        #pragma unroll
        for (int hh = 0; hh < H; ++hh) {
            float a = leaky(als[s * H + hh] + aldv[hh]);
            float nm = fmaxf(m[hh], a);
            ss[hh] = ss[hh] * __expf(m[hh] - nm) + __expf(a - nm);
            m[hh] = nm;
        }
    }
    #pragma unroll
    for (int hh = 0; hh < H; ++hh) {
        for (int off = 32; off; off >>= 1) {
            float om = __shfl_xor(m[hh], off, 64);
            float os = __shfl_xor(ss[hh], off, 64);
            float nm = fmaxf(m[hh], om);
            ss[hh] = ss[hh] * __expf(m[hh] - nm) + os * __expf(om - nm);
            m[hh] = nm;
        }
    }
    float inv[H];
    #pragma unroll
    for (int hh = 0; hh < H; ++hh) inv[hh] = 1.f / (ss[hh] + 1e-16f);

    int ch = lane;
    bool act = ch < CT;
    int hh = act ? ch / C : 0;
    float aldh = pick(aldv, hh), mh = pick(m, hh), invh = pick(inv, hh);

    float acc = 0.f;
    for (int i = beg; i < end; ++i) {
        int s = srcs[i];
        float a = leaky(als[s * H + hh] + aldh);
        float w = __expf(a - mh) * invh;
        if (act) acc += h[(long)s * CT + ch] * w;
    }
    if (act) out[(long)node * CT + ch] = acc + bias[ch];
}

// ---------------------------------------------------------------------------
// Layer 3 linear: relu(out2) @ W3 -> h3[4]; als3/ald3 dots.
// ---------------------------------------------------------------------------
__global__ void k_lin3f(const float* __restrict__ out2, const float* __restrict__ W3,
                        const float* __restrict__ as3, const float* __restrict__ ad3,
                        float* __restrict__ h3, float* __restrict__ als,
                        float* __restrict__ ald, int n) {
    int node = blockIdx.x * blockDim.x + threadIdx.x;
    if (node >= n) return;
    float a0 = 0.f, a1 = 0.f, a2 = 0.f, a3 = 0.f;
    #pragma unroll 1
    for (int c = 0; c < 54; ++c) {
        float t = fmaxf(out2[node * 54 + c], 0.f);
        a0 += t * W3[c * 4 + 0];
        a1 += t * W3[c * 4 + 1];
        a2 += t * W3[c * 4 + 2];
        a3 += t * W3[c * 4 + 3];
    }
    h3[node * 4 + 0] = a0; h3[node * 4 + 1] = a1;
    h3[node * 4 + 2] = a2; h3[node * 4 + 3] = a3;
    als[node] = a0 * as3[0] + a1 * as3[1] + a2 * as3[2] + a3 * as3[3];
    ald[node] = a0 * ad3[0] + a1 * ad3[1] + a2 * ad3[2] + a3 * ad3[3];
}

// ---------------------------------------------------------------------------
// Layer 3 aggregation fused with global max pool. 16 edge slots x 4 channels.
// ---------------------------------------------------------------------------
__device__ __forceinline__ unsigned f2mono(float f) {
    unsigned u = __float_as_uint(f);
    return u ^ ((u >> 31) ? 0xFFFFFFFFu : 0x80000000u);
}
__device__ __forceinline__ float mono2f(unsigned u) {
    u = (u & 0x80000000u) ? (u ^ 0x80000000u) : ~u;
    return __uint_as_float(u);
}

__global__ void k_pool_init(unsigned* __restrict__ genc) {
    int i = blockIdx.x * blockDim.x + threadIdx.x;
    if (i < N_GRAPHS * 4) genc[i] = f2mono(-1e9f);
}

__global__ void k_agg3pool(const int* __restrict__ rp, const int* __restrict__ srcs,
                           const float* __restrict__ h3, const float* __restrict__ als,
                           const float* __restrict__ ald, const float* __restrict__ b3,
                           const int* __restrict__ batch, unsigned* __restrict__ genc, int n) {
    int wid = threadIdx.x >> 6, lane = threadIdx.x & 63;
    int node = blockIdx.x * (blockDim.x >> 6) + wid;
    if (node >= n) return;
    int beg = rp[node], end = rp[node + 1];
    float aldv = ald[node];

    float m = -1e30f, ss = 0.f;
    for (int i = beg + lane; i < end; i += 64) {
        int s = srcs[i];
        float a = leaky(als[s] + aldv);
        float nm = fmaxf(m, a);
        ss = ss * __expf(m - nm) + __expf(a - nm);
        m = nm;
    }
    for (int off = 32; off; off >>= 1) {
        float om = __shfl_xor(m, off, 64);
        float os = __shfl_xor(ss, off, 64);
        float nm = fmaxf(m, om);
        ss = ss * __expf(m - nm) + os * __expf(om - nm);
        m = nm;
    }
    float inv = 1.f / (ss + 1e-16f);

    int es = lane >> 2, k = lane & 3;   // 16 edge slots x 4 channels
    float acc = 0.f;
    for (int i = beg + es; i < end; i += 16) {
        int s = srcs[i];
        float a = leaky(als[s] + aldv);
        float w = __expf(a - m) * inv;
        acc += h3[s * 4 + k] * w;
    }
    #pragma unroll
    for (int off = 4; off < 64; off <<= 1) acc += __shfl_xor(acc, off, 64);
    if (lane < 4) {
        float v = acc + b3[lane];
        atomicMax(&genc[batch[node] * 4 + lane], f2mono(v));
    }
}

__global__ void k_final(const unsigned* __restrict__ genc, float* __restrict__ out) {
    int g = threadIdx.x;   // 256 threads, one per graph
    float v[4];
    #pragma unroll
    for (int c = 0; c < 4; ++c) v[c] = mono2f(genc[g * 4 + c]);
    float mx = fmaxf(fmaxf(v[0], v[1]), fmaxf(v[2], v[3]));
    float s = 0.f;
    #pragma unroll
    for (int c = 0; c < 4; ++c) s += expf(v[c] - mx);
    float l = mx + logf(s);
    #pragma unroll
    for (int c = 0; c < 4; ++c) out[g * 4 + c] = v[c] - l;
}

// ---------------------------------------------------------------------------
extern "C" void kernel_launch(void* const* d_in, const int* in_sizes, int n_in,
                              void* d_out, int out_size, void* d_ws, size_t ws_size,
                              hipStream_t stream) {
    const float* x     = (const float*)d_in[0];
    const int*   ei    = (const int*)d_in[1];     // [2, E] flat
    const int*   batch = (const int*)d_in[2];
    const float* W1    = (const float*)d_in[3];
    const float* as1   = (const float*)d_in[4];
    const float* ad1   = (const float*)d_in[5];
    const float* b1    = (const float*)d_in[6];
    const float* W2    = (const float*)d_in[7];
    const float* as2   = (const float*)d_in[8];
    const float* ad2   = (const float*)d_in[9];
    const float* b2    = (const float*)d_in[10];
    const float* W3    = (const float*)d_in[11];
    const float* as3   = (const float*)d_in[12];
    const float* ad3   = (const float*)d_in[13];
    const float* b3    = (const float*)d_in[14];
    float* out = (float*)d_out;

    const int* src = ei;
    const int* dst = ei + N_EDGES;

    char* base = (char*)d_ws;
    size_t off = 0;
    auto alloc = [&](size_t bytes) -> char* {
        char* p = base + off;
        off = (off + bytes + 255) & ~(size_t)255;
        return p;
    };
    int*      counts  = (int*)alloc((size_t)N_NODES * 4);
    int*      fill    = (int*)alloc((size_t)N_NODES * 4);
    int*      row_ptr = (int*)alloc((size_t)(N_NODES + 1) * 4);
    int*      srcs    = (int*)alloc((size_t)E_TOT * 4);
    int*      bsum    = (int*)alloc(512 * 4);
    int*      boff    = (int*)alloc(512 * 4);
    float*    als     = (float*)alloc((size_t)N_NODES * 3 * 4);
    float*    ald     = (float*)alloc((size_t)N_NODES * 3 * 4);
    float*    aggx    = (float*)alloc((size_t)N_NODES * 27 * 4);
    float*    h2      = (float*)alloc((size_t)N_NODES * 54 * 4);
    float*    out2    = (float*)alloc((size_t)N_NODES * 54 * 4);
    float*    h3      = (float*)alloc((size_t)N_NODES * 4 * 4);
    unsigned* genc    = (unsigned*)alloc((size_t)N_GRAPHS * 4 * 4);
    if (off > ws_size) return;

    const int TB = 256;
    const int nb_n  = (N_NODES + TB - 1) / TB;      // 313
    const int nb_et = (E_TOT + TB - 1) / TB;
    const int nb_w  = (N_NODES + 3) / 4;            // 4 node-waves per block

    // --- CSR build ---
    hipMemsetAsync(counts, 0, (size_t)N_NODES * 4, stream);
    hipMemsetAsync(fill,   0, (size_t)N_NODES * 4, stream);
    k_hist<<<nb_et, TB, 0, stream>>>(dst, counts);
    k_scan_block<<<nb_n, SCAN_B, 0, stream>>>(counts, row_ptr, bsum, N_NODES);
    k_scan_tops<<<1, 512, 0, stream>>>(bsum, boff, nb_n);
    k_scan_add<<<nb_n, SCAN_B, 0, stream>>>(row_ptr, boff, N_NODES);
    k_scatter<<<nb_et, TB, 0, stream>>>(src, dst, row_ptr, fill, srcs);

    // --- layer 1 (factorized: aggregate x, multiply by W1 inside lin2f) ---
    k_pre1<<<nb_n, TB, 0, stream>>>(x, W1, as1, ad1, als, ald, N_NODES);
    k_agg1x<<<nb_w, TB, 0, stream>>>(row_ptr, srcs, x, als, ald, aggx, N_NODES);

    // --- layer 2 ---
    k_lin2f<<<nb_n, TB, 0, stream>>>(aggx, W1, b1, W2, as2, ad2, h2, als, ald, N_NODES);
    k_agg<3, 18><<<nb_w, TB, 0, stream>>>(row_ptr, srcs, h2, als, ald, b2, out2, N_NODES);

    // --- layer 3 + pool ---
    k_pool_init<<<(N_GRAPHS * 4 + TB - 1) / TB, TB, 0, stream>>>(genc);
    k_lin3f<<<nb_n, TB, 0, stream>>>(out2, W3, as3, ad3, h3, als, ald, N_NODES);
    k_agg3pool<<<nb_w, TB, 0, stream>>>(row_ptr, srcs, h3, als, ald, b3, batch, genc, N_NODES);
    k_final<<<1, N_GRAPHS, 0, stream>>>(genc, out);
}

// Round 5
// 641.999 us; speedup vs baseline: 1.9080x; 1.3619x over previous
//
#include <hip/hip_runtime.h>
#include <hip/hip_bf16.h>

#define N_NODES 80000
#define N_EDGES 1280000
#define E_TOT   (N_EDGES + N_NODES)   // + self loops
#define N_GRAPHS 256
#define NEG_SLOPE 0.2f

// leaky_relu(a) = max(a, 0.2*a)  (valid since 0<slope<1)
__device__ __forceinline__ float leaky(float a) { return fmaxf(a, NEG_SLOPE * a); }

// pick arr[h] with runtime h from a static-unrolled register array (no scratch)
template <int H>
__device__ __forceinline__ float pick(const float (&arr)[H], int h) {
    float r = arr[0];
    #pragma unroll
    for (int j = 1; j < H; ++j) r = (h == j) ? arr[j] : r;
    return r;
}

// ---------------------------------------------------------------------------
// CSR build (by dst). Self-loops appended as virtual edges i in [E, E+N).
// ---------------------------------------------------------------------------
__global__ void k_hist(const int* __restrict__ dst, int* __restrict__ counts) {
    int i = blockIdx.x * blockDim.x + threadIdx.x;
    if (i >= E_TOT) return;
    int d = (i < N_EDGES) ? dst[i] : (i - N_EDGES);
    atomicAdd(&counts[d], 1);
}

#define SCAN_B 256
__global__ void k_scan_block(const int* __restrict__ counts, int* __restrict__ rp,
                             int* __restrict__ bsum, int n) {
    __shared__ int sa[SCAN_B], sb[SCAN_B];
    int tid = threadIdx.x;
    int gi = blockIdx.x * SCAN_B + tid;
    int v = (gi < n) ? counts[gi] : 0;
    sa[tid] = v;
    __syncthreads();
    int* cur = sa; int* nxt = sb;
    #pragma unroll
    for (int d = 1; d < SCAN_B; d <<= 1) {
        int t = cur[tid];
        if (tid >= d) t += cur[tid - d];
        nxt[tid] = t;
        __syncthreads();
        int* tmp = cur; cur = nxt; nxt = tmp;
    }
    if (gi < n) rp[gi] = cur[tid] - v;            // block-local exclusive
    if (tid == SCAN_B - 1) bsum[blockIdx.x] = cur[tid];
}

__global__ void k_scan_tops(const int* __restrict__ bsum, int* __restrict__ boff, int nb) {
    __shared__ int sa[512], sb[512];
    int tid = threadIdx.x;
    int v = (tid < nb) ? bsum[tid] : 0;
    sa[tid] = v;
    __syncthreads();
    int* cur = sa; int* nxt = sb;
    #pragma unroll
    for (int d = 1; d < 512; d <<= 1) {
        int t = cur[tid];
        if (tid >= d) t += cur[tid - d];
        nxt[tid] = t;
        __syncthreads();
        int* tmp = cur; cur = nxt; nxt = tmp;
    }
    if (tid < nb) boff[tid] = cur[tid] - v;
}

__global__ void k_scan_add(int* __restrict__ rp, const int* __restrict__ boff, int n) {
    int gi = blockIdx.x * blockDim.x + threadIdx.x;
    if (gi < n) rp[gi] += boff[blockIdx.x];
    if (gi == 0) rp[n] = E_TOT;
}

__global__ void k_scatter(const int* __restrict__ src, const int* __restrict__ dst,
                          const int* __restrict__ rp, int* __restrict__ fill,
                          int* __restrict__ srcs) {
    int i = blockIdx.x * blockDim.x + threadIdx.x;
    if (i >= E_TOT) return;
    int s, d;
    if (i < N_EDGES) { s = src[i]; d = dst[i]; }
    else             { s = i - N_EDGES; d = s; }
    int pos = rp[d] + atomicAdd(&fill[d], 1);
    srcs[pos] = s;
}

// ---------------------------------------------------------------------------
// Layer 1 pre-pass: als1/ald1 directly from x via projected 3x9 matrices
// ps[h][k] = sum_c W1[k, h*45+c] * a_src[h,c]   (h1 never materialized!)
// ---------------------------------------------------------------------------
__global__ void k_pre1(const float* __restrict__ x, const float* __restrict__ W1,
                       const float* __restrict__ as1, const float* __restrict__ ad1,
                       float* __restrict__ als, float* __restrict__ ald, int n) {
    __shared__ float ps[27], pd[27];
    int t = threadIdx.x;
    if (t < 27) {
        int h = t / 9, k = t % 9;
        float s = 0.f, d = 0.f;
        for (int c = 0; c < 45; ++c) {
            float w = W1[k * 135 + h * 45 + c];
            s += w * as1[h * 45 + c];
            d += w * ad1[h * 45 + c];
        }
        ps[t] = s; pd[t] = d;
    }
    __syncthreads();
    int node = blockIdx.x * blockDim.x + t;
    if (node >= n) return;
    float xr[9];
    #pragma unroll
    for (int k = 0; k < 9; ++k) xr[k] = x[node * 9 + k];
    #pragma unroll
    for (int h = 0; h < 3; ++h) {
        float s = 0.f, d = 0.f;
        #pragma unroll
        for (int k = 0; k < 9; ++k) { s += xr[k] * ps[h * 9 + k]; d += xr[k] * pd[h * 9 + k]; }
        als[node * 3 + h] = s;
        ald[node * 3 + h] = d;
    }
}

// ---------------------------------------------------------------------------
// Layer 1 aggregation over x (factorized): aggx[n, h*9+k] = sum_e w_h(e) x[src,k]
// One wave per node. Pass C: 2 edge slots x 27 channels, UNROLLED x4
// (8 edges in flight per wave -> memory-level parallelism for latency hiding).
// ---------------------------------------------------------------------------
__global__ void k_agg1x(const int* __restrict__ rp, const int* __restrict__ srcs,
                        const float* __restrict__ x, const float* __restrict__ als,
                        const float* __restrict__ ald, float* __restrict__ aggx, int n) {
    int wid = threadIdx.x >> 6, lane = threadIdx.x & 63;
    int node = blockIdx.x * (blockDim.x >> 6) + wid;
    if (node >= n) return;
    int beg = rp[node], end = rp[node + 1];

    float aldv[3];
    #pragma unroll
    for (int h = 0; h < 3; ++h) aldv[h] = ald[node * 3 + h];

    // online per-head max + sum-of-exp
    float m[3], ss[3];
    #pragma unroll
    for (int h = 0; h < 3; ++h) { m[h] = -1e30f; ss[h] = 0.f; }
    for (int i = beg + lane; i < end; i += 64) {
        int s = srcs[i];
        #pragma unroll
        for (int h = 0; h < 3; ++h) {
            float a = leaky(als[s * 3 + h] + aldv[h]);
            float nm = fmaxf(m[h], a);
            ss[h] = ss[h] * __expf(m[h] - nm) + __expf(a - nm);
            m[h] = nm;
        }
    }
    #pragma unroll
    for (int h = 0; h < 3; ++h) {
        for (int off = 32; off; off >>= 1) {
            float om = __shfl_xor(m[h], off, 64);
            float os = __shfl_xor(ss[h], off, 64);
            float nm = fmaxf(m[h], om);
            ss[h] = ss[h] * __expf(m[h] - nm) + os * __expf(om - nm);
            m[h] = nm;
        }
    }
    float inv[3];
    #pragma unroll
    for (int h = 0; h < 3; ++h) inv[h] = 1.f / (ss[h] + 1e-16f);

    // channel-parallel: li in [0,27): (h, k); two edge slots (es = lane>>5)
    int es = lane >> 5, li = lane & 31;
    int lic = li < 27 ? li : 26;     // clamp keeps loads in-bounds, no branch
    int hh = lic / 9;
    int kk = lic % 9;
    float aldh = pick(aldv, hh), mh = pick(m, hh), invh = pick(inv, hh);

    float acc = 0.f;
    int i = beg + es;
    for (; i + 6 < end; i += 8) {   // 4 edges per slot in flight
        int s0 = srcs[i], s1 = srcs[i + 2], s2 = srcs[i + 4], s3 = srcs[i + 6];
        float a0 = leaky(als[s0 * 3 + hh] + aldh);
        float a1 = leaky(als[s1 * 3 + hh] + aldh);
        float a2 = leaky(als[s2 * 3 + hh] + aldh);
        float a3 = leaky(als[s3 * 3 + hh] + aldh);
        float x0 = x[s0 * 9 + kk], x1 = x[s1 * 9 + kk];
        float x2 = x[s2 * 9 + kk], x3 = x[s3 * 9 + kk];
        float w0 = __expf(a0 - mh) * invh, w1 = __expf(a1 - mh) * invh;
        float w2 = __expf(a2 - mh) * invh, w3 = __expf(a3 - mh) * invh;
        acc += x0 * w0 + x1 * w1 + x2 * w2 + x3 * w3;
    }
    for (; i < end; i += 2) {
        int s = srcs[i];
        float a = leaky(als[s * 3 + hh] + aldh);
        float w = __expf(a - mh) * invh;
        acc += x[s * 9 + kk] * w;
    }
    acc += __shfl_xor(acc, 32, 64);
    if (lane < 27) aggx[node * 27 + lane] = acc;
}

// ---------------------------------------------------------------------------
// Fused: out1 = aggx @ W1 + b1 -> ReLU -> h2 = out1 @ W2 ; als2/ald2 dots.
// Thread per node. W reads are wave-uniform -> scalar loads via L2/K$.
// ---------------------------------------------------------------------------
__global__ void k_lin2f(const float* __restrict__ aggx, const float* __restrict__ W1,
                        const float* __restrict__ b1, const float* __restrict__ W2,
                        const float* __restrict__ as2, const float* __restrict__ ad2,
                        float* __restrict__ h2, float* __restrict__ als,
                        float* __restrict__ ald, int n) {
    int node = blockIdx.x * blockDim.x + threadIdx.x;
    if (node >= n) return;
    float ax[27];
    #pragma unroll
    for (int j = 0; j < 27; ++j) ax[j] = aggx[node * 27 + j];
    float acc[54];
    #pragma unroll
    for (int c = 0; c < 54; ++c) acc[c] = 0.f;
    #pragma unroll
    for (int h = 0; h < 3; ++h) {          // must be unrolled: ax[] static idx
        #pragma unroll 1
        for (int c0 = 0; c0 < 45; ++c0) {
            int col = h * 45 + c0;
            float t = b1[col];
            #pragma unroll
            for (int k = 0; k < 9; ++k) t += ax[h * 9 + k] * W1[k * 135 + col];
            t = fmaxf(t, 0.f);             // ReLU between layers
            #pragma unroll
            for (int cc = 0; cc < 54; ++cc) acc[cc] += t * W2[col * 54 + cc];
        }
    }
    float as_[3] = {0.f, 0.f, 0.f}, ad_[3] = {0.f, 0.f, 0.f};
    #pragma unroll
    for (int c = 0; c < 54; ++c) {
        h2[node * 54 + c] = acc[c];
        as_[c / 18] += acc[c] * as2[c];
        ad_[c / 18] += acc[c] * ad2[c];
    }
    #pragma unroll
    for (int h = 0; h < 3; ++h) { als[node * 3 + h] = as_[h]; ald[node * 3 + h] = ad_[h]; }
}

// ---------------------------------------------------------------------------
// Layer 2 aggregation: 2 edge slots x 27 float2 channels, UNROLLED x4.
// h2 rows are 54 floats = 27 float2 (8B loads, 8 edges in flight per wave).
// ---------------------------------------------------------------------------
__global__ void k_agg2(const int* __restrict__ rp, const int* __restrict__ srcs,
                       const float* __restrict__ h, const float* __restrict__ als,
                       const float* __restrict__ ald, const float* __restrict__ bias,
                       float* __restrict__ out, int n) {
    int wid = threadIdx.x >> 6, lane = threadIdx.x & 63;
    int node = blockIdx.x * (blockDim.x >> 6) + wid;
    if (node >= n) return;
    int beg = rp[node], end = rp[node + 1];

    float aldv[3];
    #pragma unroll
    for (int hh = 0; hh < 3; ++hh) aldv[hh] = ald[node * 3 + hh];

    float m[3], ss[3];
    #pragma unroll
    for (int hh = 0; hh < 3; ++hh) { m[hh] = -1e30f; ss[hh] = 0.f; }
    for (int i = beg + lane; i < end; i += 64) {
        int s = srcs[i];
        #pragma unroll
        for (int hh = 0; hh < 3; ++hh) {
            float a = leaky(als[s * 3 + hh] + aldv[hh]);
            float nm = fmaxf(m[hh], a);
            ss[hh] = ss[hh] * __expf(m[hh] - nm) + __expf(a - nm);
            m[hh] = nm;
        }
    }
    #pragma unroll
    for (int hh = 0; hh < 3; ++hh) {
        for (int off = 32; off; off >>= 1) {
            float om = __shfl_xor(m[hh], off, 64);
            float os = __shfl_xor(ss[hh], off, 64);
            float nm = fmaxf(m[hh], om);
            ss[hh] = ss[hh] * __expf(m[hh] - nm) + os * __expf(om - nm);
            m[hh] = nm;
        }
    }
    float inv[3];
    #pragma unroll
    for (int hh = 0; hh < 3; ++hh) inv[hh] = 1.f / (ss[hh] + 1e-16f);

    // pass C: lane -> (edge slot es, float2-channel li); ch pair (2li, 2li+1)
    // never straddles a head boundary (18 even), so hh = li/9.
    int es = lane >> 5, li = lane & 31;
    bool act = li < 27;
    int lic = act ? li : 26;
    int hh = lic / 9;
    float aldh = pick(aldv, hh), mh = pick(m, hh), invh = pick(inv, hh);
    const float2* hv = (const float2*)h;

    float accx = 0.f, accy = 0.f;
    int i = beg + es;
    for (; i + 6 < end; i += 8) {   // 4 edges per slot in flight
        int s0 = srcs[i], s1 = srcs[i + 2], s2 = srcs[i + 4], s3 = srcs[i + 6];
        float a0 = leaky(als[s0 * 3 + hh] + aldh);
        float a1 = leaky(als[s1 * 3 + hh] + aldh);
        float a2 = leaky(als[s2 * 3 + hh] + aldh);
        float a3 = leaky(als[s3 * 3 + hh] + aldh);
        float2 v0 = hv[s0 * 27 + lic], v1 = hv[s1 * 27 + lic];
        float2 v2 = hv[s2 * 27 + lic], v3 = hv[s3 * 27 + lic];
        float w0 = __expf(a0 - mh) * invh, w1 = __expf(a1 - mh) * invh;
        float w2 = __expf(a2 - mh) * invh, w3 = __expf(a3 - mh) * invh;
        accx += v0.x * w0 + v1.x * w1 + v2.x * w2 + v3.x * w3;
        accy += v0.y * w0 + v1.y * w1 + v2.y * w2 + v3.y * w3;
    }
    for (; i < end; i += 2) {
        int s = srcs[i];
        float a = leaky(als[s * 3 + hh] + aldh);
        float w = __expf(a - mh) * invh;
        float2 v = hv[s * 27 + lic];
        accx += v.x * w;
        accy += v.y * w;
    }
    accx += __shfl_xor(accx, 32, 64);
    accy += __shfl_xor(accy, 32, 64);
    if (act && es == 0) {
        float2 b = ((const float2*)bias)[li];
        float2 o; o.x = accx + b.x; o.y = accy + b.y;
        ((float2*)out)[(long)node * 27 + li] = o;
    }
}

// ---------------------------------------------------------------------------
// Layer 3 linear: relu(out2) @ W3 -> h3[4]; als3/ald3 dots.
// ---------------------------------------------------------------------------
__global__ void k_lin3f(const float* __restrict__ out2, const float* __restrict__ W3,
                        const float* __restrict__ as3, const float* __restrict__ ad3,
                        float* __restrict__ h3, float* __restrict__ als,
                        float* __restrict__ ald, int n) {
    int node = blockIdx.x * blockDim.x + threadIdx.x;
    if (node >= n) return;
    float a0 = 0.f, a1 = 0.f, a2 = 0.f, a3 = 0.f;
    #pragma unroll 1
    for (int c = 0; c < 54; ++c) {
        float t = fmaxf(out2[node * 54 + c], 0.f);
        a0 += t * W3[c * 4 + 0];
        a1 += t * W3[c * 4 + 1];
        a2 += t * W3[c * 4 + 2];
        a3 += t * W3[c * 4 + 3];
    }
    h3[node * 4 + 0] = a0; h3[node * 4 + 1] = a1;
    h3[node * 4 + 2] = a2; h3[node * 4 + 3] = a3;
    als[node] = a0 * as3[0] + a1 * as3[1] + a2 * as3[2] + a3 * as3[3];
    ald[node] = a0 * ad3[0] + a1 * ad3[1] + a2 * ad3[2] + a3 * ad3[3];
}

// ---------------------------------------------------------------------------
// Layer 3 aggregation fused with global max pool.
// Pass C: 64 edge slots; each lane loads a full float4 h3 row + own weight.
// Most nodes (deg<=64) finish in ONE memory round.
// ---------------------------------------------------------------------------
__device__ __forceinline__ unsigned f2mono(float f) {
    unsigned u = __float_as_uint(f);
    return u ^ ((u >> 31) ? 0xFFFFFFFFu : 0x80000000u);
}
__device__ __forceinline__ float mono2f(unsigned u) {
    u = (u & 0x80000000u) ? (u ^ 0x80000000u) : ~u;
    return __uint_as_float(u);
}

__global__ void k_pool_init(unsigned* __restrict__ genc) {
    int i = blockIdx.x * blockDim.x + threadIdx.x;
    if (i < N_GRAPHS * 4) genc[i] = f2mono(-1e9f);
}

__global__ void k_agg3pool(const int* __restrict__ rp, const int* __restrict__ srcs,
                           const float* __restrict__ h3, const float* __restrict__ als,
                           const float* __restrict__ ald, const float* __restrict__ b3,
                           const int* __restrict__ batch, unsigned* __restrict__ genc, int n) {
    int wid = threadIdx.x >> 6, lane = threadIdx.x & 63;
    int node = blockIdx.x * (blockDim.x >> 6) + wid;
    if (node >= n) return;
    int beg = rp[node], end = rp[node + 1];
    float aldv = ald[node];

    float m = -1e30f, ss = 0.f;
    for (int i = beg + lane; i < end; i += 64) {
        int s = srcs[i];
        float a = leaky(als[s] + aldv);
        float nm = fmaxf(m, a);
        ss = ss * __expf(m - nm) + __expf(a - nm);
        m = nm;
    }
    for (int off = 32; off; off >>= 1) {
        float om = __shfl_xor(m, off, 64);
        float os = __shfl_xor(ss, off, 64);
        float nm = fmaxf(m, om);
        ss = ss * __expf(m - nm) + os * __expf(om - nm);
        m = nm;
    }
    float inv = 1.f / (ss + 1e-16f);

    // 64 edge slots: per lane one edge -> weight + full float4 row
    float ax = 0.f, ay = 0.f, az = 0.f, aw = 0.f;
    const float4* h4 = (const float4*)h3;
    for (int i = beg + lane; i < end; i += 64) {
        int s = srcs[i];
        float a = leaky(als[s] + aldv);
        float w = __expf(a - m) * inv;
        float4 v = h4[s];
        ax += v.x * w; ay += v.y * w; az += v.z * w; aw += v.w * w;
    }
    #pragma unroll
    for (int off = 32; off; off >>= 1) {
        ax += __shfl_xor(ax, off, 64);
        ay += __shfl_xor(ay, off, 64);
        az += __shfl_xor(az, off, 64);
        aw += __shfl_xor(aw, off, 64);
    }
    if (lane < 4) {
        float v = (lane == 0) ? ax : (lane == 1) ? ay : (lane == 2) ? az : aw;
        atomicMax(&genc[batch[node] * 4 + lane], f2mono(v + b3[lane]));
    }
}

__global__ void k_final(const unsigned* __restrict__ genc, float* __restrict__ out) {
    int g = threadIdx.x;   // 256 threads, one per graph
    float v[4];
    #pragma unroll
    for (int c = 0; c < 4; ++c) v[c] = mono2f(genc[g * 4 + c]);
    float mx = fmaxf(fmaxf(v[0], v[1]), fmaxf(v[2], v[3]));
    float s = 0.f;
    #pragma unroll
    for (int c = 0; c < 4; ++c) s += expf(v[c] - mx);
    float l = mx + logf(s);
    #pragma unroll
    for (int c = 0; c < 4; ++c) out[g * 4 + c] = v[c] - l;
}

// ---------------------------------------------------------------------------
extern "C" void kernel_launch(void* const* d_in, const int* in_sizes, int n_in,
                              void* d_out, int out_size, void* d_ws, size_t ws_size,
                              hipStream_t stream) {
    const float* x     = (const float*)d_in[0];
    const int*   ei    = (const int*)d_in[1];     // [2, E] flat
    const int*   batch = (const int*)d_in[2];
    const float* W1    = (const float*)d_in[3];
    const float* as1   = (const float*)d_in[4];
    const float* ad1   = (const float*)d_in[5];
    const float* b1    = (const float*)d_in[6];
    const float* W2    = (const float*)d_in[7];
    const float* as2   = (const float*)d_in[8];
    const float* ad2   = (const float*)d_in[9];
    const float* b2    = (const float*)d_in[10];
    const float* W3    = (const float*)d_in[11];
    const float* as3   = (const float*)d_in[12];
    const float* ad3   = (const float*)d_in[13];
    const float* b3    = (const float*)d_in[14];
    float* out = (float*)d_out;

    const int* src = ei;
    const int* dst = ei + N_EDGES;

    char* base = (char*)d_ws;
    size_t off = 0;
    auto alloc = [&](size_t bytes) -> char* {
        char* p = base + off;
        off = (off + bytes + 255) & ~(size_t)255;
        return p;
    };
    int*      counts  = (int*)alloc((size_t)N_NODES * 4);
    int*      fill    = (int*)alloc((size_t)N_NODES * 4);
    int*      row_ptr = (int*)alloc((size_t)(N_NODES + 1) * 4);
    int*      srcs    = (int*)alloc((size_t)E_TOT * 4);
    int*      bsum    = (int*)alloc(512 * 4);
    int*      boff    = (int*)alloc(512 * 4);
    float*    als     = (float*)alloc((size_t)N_NODES * 3 * 4);
    float*    ald     = (float*)alloc((size_t)N_NODES * 3 * 4);
    float*    aggx    = (float*)alloc((size_t)N_NODES * 27 * 4);
    float*    h2      = (float*)alloc((size_t)N_NODES * 54 * 4);
    float*    out2    = (float*)alloc((size_t)N_NODES * 54 * 4);
    float*    h3      = (float*)alloc((size_t)N_NODES * 4 * 4);
    unsigned* genc    = (unsigned*)alloc((size_t)N_GRAPHS * 4 * 4);
    if (off > ws_size) return;

    const int TB = 256;
    const int nb_n  = (N_NODES + TB - 1) / TB;      // 313
    const int nb_et = (E_TOT + TB - 1) / TB;
    const int nb_w  = (N_NODES + 3) / 4;            // 4 node-waves per block

    // --- CSR build ---
    hipMemsetAsync(counts, 0, (size_t)N_NODES * 4, stream);
    hipMemsetAsync(fill,   0, (size_t)N_NODES * 4, stream);
    k_hist<<<nb_et, TB, 0, stream>>>(dst, counts);
    k_scan_block<<<nb_n, SCAN_B, 0, stream>>>(counts, row_ptr, bsum, N_NODES);
    k_scan_tops<<<1, 512, 0, stream>>>(bsum, boff, nb_n);
    k_scan_add<<<nb_n, SCAN_B, 0, stream>>>(row_ptr, boff, N_NODES);
    k_scatter<<<nb_et, TB, 0, stream>>>(src, dst, row_ptr, fill, srcs);

    // --- layer 1 (factorized: aggregate x, multiply by W1 inside lin2f) ---
    k_pre1<<<nb_n, TB, 0, stream>>>(x, W1, as1, ad1, als, ald, N_NODES);
    k_agg1x<<<nb_w, TB, 0, stream>>>(row_ptr, srcs, x, als, ald, aggx, N_NODES);

    // --- layer 2 ---
    k_lin2f<<<nb_n, TB, 0, stream>>>(aggx, W1, b1, W2, as2, ad2, h2, als, ald, N_NODES);
    k_agg2<<<nb_w, TB, 0, stream>>>(row_ptr, srcs, h2, als, ald, b2, out2, N_NODES);

    // --- layer 3 + pool ---
    k_pool_init<<<(N_GRAPHS * 4 + TB - 1) / TB, TB, 0, stream>>>(genc);
    k_lin3f<<<nb_n, TB, 0, stream>>>(out2, W3, as3, ad3, h3, als, ald, N_NODES);
    k_agg3pool<<<nb_w, TB, 0, stream>>>(row_ptr, srcs, h3, als, ald, b3, batch, genc, N_NODES);
    k_final<<<1, N_GRAPHS, 0, stream>>>(genc, out);
}

// Round 6
// 570.576 us; speedup vs baseline: 2.1469x; 1.1252x over previous
//
#include <hip/hip_runtime.h>
#include <hip/hip_bf16.h>

#define N_NODES 80000
#define N_EDGES 1280000
#define E_TOT   (N_EDGES + N_NODES)   // + self loops
#define N_GRAPHS 256
#define NEG_SLOPE 0.2f

// leaky_relu(a) = max(a, 0.2*a)  (valid since 0<slope<1)
__device__ __forceinline__ float leaky(float a) { return fmaxf(a, NEG_SLOPE * a); }

// pick arr[h] with runtime h from a static-unrolled register array (no scratch)
template <int H>
__device__ __forceinline__ float pick(const float (&arr)[H], int h) {
    float r = arr[0];
    #pragma unroll
    for (int j = 1; j < H; ++j) r = (h == j) ? arr[j] : r;
    return r;
}

__device__ __forceinline__ unsigned f2mono(float f) {
    unsigned u = __float_as_uint(f);
    return u ^ ((u >> 31) ? 0xFFFFFFFFu : 0x80000000u);
}
__device__ __forceinline__ float mono2f(unsigned u) {
    u = (u & 0x80000000u) ? (u ^ 0x80000000u) : ~u;
    return __uint_as_float(u);
}

// ---------------------------------------------------------------------------
// Init: zero counts/fill, init pool accumulators (replaces 2 memsets + pool_init)
// ---------------------------------------------------------------------------
__global__ void k_init(int* __restrict__ counts, int* __restrict__ fill,
                       unsigned* __restrict__ genc) {
    int i = blockIdx.x * blockDim.x + threadIdx.x;
    if (i < N_NODES) { counts[i] = 0; fill[i] = 0; }
    if (i < N_GRAPHS * 4) genc[i] = f2mono(-1e9f);
}

// ---------------------------------------------------------------------------
// CSR build (by dst). Self-loops appended as virtual edges i in [E, E+N).
// ---------------------------------------------------------------------------
__global__ void k_hist(const int* __restrict__ dst, int* __restrict__ counts) {
    int i = blockIdx.x * blockDim.x + threadIdx.x;
    if (i >= E_TOT) return;
    int d = (i < N_EDGES) ? dst[i] : (i - N_EDGES);
    atomicAdd(&counts[d], 1);
}

#define SCAN_B 256
__global__ void k_scan_block(const int* __restrict__ counts, int* __restrict__ rp,
                             int* __restrict__ bsum, int n) {
    __shared__ int sa[SCAN_B], sb[SCAN_B];
    int tid = threadIdx.x;
    int gi = blockIdx.x * SCAN_B + tid;
    int v = (gi < n) ? counts[gi] : 0;
    sa[tid] = v;
    __syncthreads();
    int* cur = sa; int* nxt = sb;
    #pragma unroll
    for (int d = 1; d < SCAN_B; d <<= 1) {
        int t = cur[tid];
        if (tid >= d) t += cur[tid - d];
        nxt[tid] = t;
        __syncthreads();
        int* tmp = cur; cur = nxt; nxt = tmp;
    }
    if (gi < n) rp[gi] = cur[tid] - v;            // block-local exclusive
    if (tid == SCAN_B - 1) bsum[blockIdx.x] = cur[tid];
}

__global__ void k_scan_tops(const int* __restrict__ bsum, int* __restrict__ boff, int nb) {
    __shared__ int sa[512], sb[512];
    int tid = threadIdx.x;
    int v = (tid < nb) ? bsum[tid] : 0;
    sa[tid] = v;
    __syncthreads();
    int* cur = sa; int* nxt = sb;
    #pragma unroll
    for (int d = 1; d < 512; d <<= 1) {
        int t = cur[tid];
        if (tid >= d) t += cur[tid - d];
        nxt[tid] = t;
        __syncthreads();
        int* tmp = cur; cur = nxt; nxt = tmp;
    }
    if (tid < nb) boff[tid] = cur[tid] - v;
}

// scan finalize FUSED with layer-1 pre-pass (same 313x256 grid):
// rp[gi] += boff[block]; als1/ald1 from x via projected 3x9 matrices
// ps[h][k] = sum_c W1[k, h*45+c] * a_src[h,c]   (h1 never materialized)
__global__ void k_scan_add_pre1(int* __restrict__ rp, const int* __restrict__ boff,
                                const float* __restrict__ x, const float* __restrict__ W1,
                                const float* __restrict__ as1, const float* __restrict__ ad1,
                                float* __restrict__ als, float* __restrict__ ald, int n) {
    __shared__ float ps[27], pd[27];
    int t = threadIdx.x;
    int gi = blockIdx.x * blockDim.x + t;
    if (gi < n) rp[gi] += boff[blockIdx.x];
    if (gi == 0) rp[n] = E_TOT;
    if (t < 27) {
        int h = t / 9, k = t % 9;
        float s = 0.f, d = 0.f;
        for (int c = 0; c < 45; ++c) {
            float w = W1[k * 135 + h * 45 + c];
            s += w * as1[h * 45 + c];
            d += w * ad1[h * 45 + c];
        }
        ps[t] = s; pd[t] = d;
    }
    __syncthreads();
    if (gi >= n) return;
    float xr[9];
    #pragma unroll
    for (int k = 0; k < 9; ++k) xr[k] = x[gi * 9 + k];
    #pragma unroll
    for (int h = 0; h < 3; ++h) {
        float s = 0.f, d = 0.f;
        #pragma unroll
        for (int k = 0; k < 9; ++k) { s += xr[k] * ps[h * 9 + k]; d += xr[k] * pd[h * 9 + k]; }
        als[gi * 3 + h] = s;
        ald[gi * 3 + h] = d;
    }
}

__global__ void k_scatter(const int* __restrict__ src, const int* __restrict__ dst,
                          const int* __restrict__ rp, int* __restrict__ fill,
                          int* __restrict__ srcs) {
    int i = blockIdx.x * blockDim.x + threadIdx.x;
    if (i >= E_TOT) return;
    int s, d;
    if (i < N_EDGES) { s = src[i]; d = dst[i]; }
    else             { s = i - N_EDGES; d = s; }
    int pos = rp[d] + atomicAdd(&fill[d], 1);
    srcs[pos] = s;
}

// ---------------------------------------------------------------------------
// Layer 1 aggregation over x (factorized): aggx[n, h*9+k] = (1/s_h) sum_e e_h(i) x[src,k]
// Max-free softmax: e = exp(leaky(a)); normalizer applied ONCE after reduce.
// Pass B: gather als, 3 exp/edge, write e -> wv, online sum (plain butterfly).
// Pass C: pure gather+FMA (wv read is CSR-indexed, independent of gather chain).
// ---------------------------------------------------------------------------
__global__ void k_agg1x(const int* __restrict__ rp, const int* __restrict__ srcs,
                        const float* __restrict__ x, const float* __restrict__ als,
                        const float* __restrict__ ald, float* __restrict__ wv,
                        float* __restrict__ aggx, int n) {
    int wid = threadIdx.x >> 6, lane = threadIdx.x & 63;
    int node = blockIdx.x * (blockDim.x >> 6) + wid;
    if (node >= n) return;
    int beg = rp[node], end = rp[node + 1];

    float aldv[3];
    #pragma unroll
    for (int h = 0; h < 3; ++h) aldv[h] = ald[node * 3 + h];

    // pass B: unnormalized weights + sum
    float ss[3] = {0.f, 0.f, 0.f};
    for (int i = beg + lane; i < end; i += 64) {
        int s = srcs[i];
        #pragma unroll
        for (int h = 0; h < 3; ++h) {
            float e = __expf(leaky(als[s * 3 + h] + aldv[h]));
            wv[i * 3 + h] = e;
            ss[h] += e;
        }
    }
    #pragma unroll
    for (int h = 0; h < 3; ++h) {
        #pragma unroll
        for (int off = 32; off; off >>= 1) ss[h] += __shfl_xor(ss[h], off, 64);
    }
    float inv[3];
    #pragma unroll
    for (int h = 0; h < 3; ++h) inv[h] = 1.f / (ss[h] + 1e-16f);

    // pass C: li in [0,27): (h, k); two edge slots (es = lane>>5), unroll x4
    int es = lane >> 5, li = lane & 31;
    int lic = li < 27 ? li : 26;     // clamp keeps loads in-bounds, no branch
    int hh = lic / 9;
    int kk = lic % 9;
    float invh = pick(inv, hh);

    float acc = 0.f;
    int i = beg + es;
    for (; i + 6 < end; i += 8) {   // 4 edges per slot in flight
        int s0 = srcs[i], s1 = srcs[i + 2], s2 = srcs[i + 4], s3 = srcs[i + 6];
        float w0 = wv[i * 3 + hh],       w1 = wv[(i + 2) * 3 + hh];
        float w2 = wv[(i + 4) * 3 + hh], w3 = wv[(i + 6) * 3 + hh];
        float x0 = x[s0 * 9 + kk], x1 = x[s1 * 9 + kk];
        float x2 = x[s2 * 9 + kk], x3 = x[s3 * 9 + kk];
        acc += x0 * w0 + x1 * w1 + x2 * w2 + x3 * w3;
    }
    for (; i < end; i += 2) {
        acc += x[srcs[i] * 9 + kk] * wv[i * 3 + hh];
    }
    acc += __shfl_xor(acc, 32, 64);
    if (lane < 27) aggx[node * 27 + lane] = acc * invh;
}

// ---------------------------------------------------------------------------
// Fused: out1 = aggx @ W1 + b1 -> ReLU -> h2 = out1 @ W2 ; als2/ald2 dots.
// Thread per node. W reads are wave-uniform -> scalar loads via L2/K$.
// ---------------------------------------------------------------------------
__global__ void k_lin2f(const float* __restrict__ aggx, const float* __restrict__ W1,
                        const float* __restrict__ b1, const float* __restrict__ W2,
                        const float* __restrict__ as2, const float* __restrict__ ad2,
                        float* __restrict__ h2, float* __restrict__ als,
                        float* __restrict__ ald, int n) {
    int node = blockIdx.x * blockDim.x + threadIdx.x;
    if (node >= n) return;
    float ax[27];
    #pragma unroll
    for (int j = 0; j < 27; ++j) ax[j] = aggx[node * 27 + j];
    float acc[54];
    #pragma unroll
    for (int c = 0; c < 54; ++c) acc[c] = 0.f;
    #pragma unroll
    for (int h = 0; h < 3; ++h) {          // must be unrolled: ax[] static idx
        #pragma unroll 1
        for (int c0 = 0; c0 < 45; ++c0) {
            int col = h * 45 + c0;
            float t = b1[col];
            #pragma unroll
            for (int k = 0; k < 9; ++k) t += ax[h * 9 + k] * W1[k * 135 + col];
            t = fmaxf(t, 0.f);             // ReLU between layers
            #pragma unroll
            for (int cc = 0; cc < 54; ++cc) acc[cc] += t * W2[col * 54 + cc];
        }
    }
    float as_[3] = {0.f, 0.f, 0.f}, ad_[3] = {0.f, 0.f, 0.f};
    #pragma unroll
    for (int c = 0; c < 54; ++c) {
        h2[node * 54 + c] = acc[c];
        as_[c / 18] += acc[c] * as2[c];
        ad_[c / 18] += acc[c] * ad2[c];
    }
    #pragma unroll
    for (int h = 0; h < 3; ++h) { als[node * 3 + h] = as_[h]; ald[node * 3 + h] = ad_[h]; }
}

// ---------------------------------------------------------------------------
// Layer 2 aggregation: max-free 2-pass; pass C = 2 slots x 27 float2, x4 unroll.
// ---------------------------------------------------------------------------
__global__ void k_agg2(const int* __restrict__ rp, const int* __restrict__ srcs,
                       const float* __restrict__ h, const float* __restrict__ als,
                       const float* __restrict__ ald, float* __restrict__ wv,
                       const float* __restrict__ bias, float* __restrict__ out, int n) {
    int wid = threadIdx.x >> 6, lane = threadIdx.x & 63;
    int node = blockIdx.x * (blockDim.x >> 6) + wid;
    if (node >= n) return;
    int beg = rp[node], end = rp[node + 1];

    float aldv[3];
    #pragma unroll
    for (int hh = 0; hh < 3; ++hh) aldv[hh] = ald[node * 3 + hh];

    float ss[3] = {0.f, 0.f, 0.f};
    for (int i = beg + lane; i < end; i += 64) {
        int s = srcs[i];
        #pragma unroll
        for (int hh = 0; hh < 3; ++hh) {
            float e = __expf(leaky(als[s * 3 + hh] + aldv[hh]));
            wv[i * 3 + hh] = e;
            ss[hh] += e;
        }
    }
    #pragma unroll
    for (int hh = 0; hh < 3; ++hh) {
        #pragma unroll
        for (int off = 32; off; off >>= 1) ss[hh] += __shfl_xor(ss[hh], off, 64);
    }
    float inv[3];
    #pragma unroll
    for (int hh = 0; hh < 3; ++hh) inv[hh] = 1.f / (ss[hh] + 1e-16f);

    // pass C: lane -> (edge slot es, float2-channel lic); pair never straddles heads
    int es = lane >> 5, li = lane & 31;
    bool act = li < 27;
    int lic = act ? li : 26;
    int hh = lic / 9;
    float invh = pick(inv, hh);
    const float2* hv = (const float2*)h;

    float accx = 0.f, accy = 0.f;
    int i = beg + es;
    for (; i + 6 < end; i += 8) {   // 4 edges per slot in flight
        int s0 = srcs[i], s1 = srcs[i + 2], s2 = srcs[i + 4], s3 = srcs[i + 6];
        float w0 = wv[i * 3 + hh],       w1 = wv[(i + 2) * 3 + hh];
        float w2 = wv[(i + 4) * 3 + hh], w3 = wv[(i + 6) * 3 + hh];
        float2 v0 = hv[s0 * 27 + lic], v1 = hv[s1 * 27 + lic];
        float2 v2 = hv[s2 * 27 + lic], v3 = hv[s3 * 27 + lic];
        accx += v0.x * w0 + v1.x * w1 + v2.x * w2 + v3.x * w3;
        accy += v0.y * w0 + v1.y * w1 + v2.y * w2 + v3.y * w3;
    }
    for (; i < end; i += 2) {
        float w = wv[i * 3 + hh];
        float2 v = hv[srcs[i] * 27 + lic];
        accx += v.x * w;
        accy += v.y * w;
    }
    accx += __shfl_xor(accx, 32, 64);
    accy += __shfl_xor(accy, 32, 64);
    if (act && es == 0) {
        float2 b = ((const float2*)bias)[li];
        float2 o; o.x = accx * invh + b.x; o.y = accy * invh + b.y;
        ((float2*)out)[(long)node * 27 + li] = o;
    }
}

// ---------------------------------------------------------------------------
// Layer 3 linear: relu(out2) @ W3 -> h3[4]; als3/ald3 dots.
// ---------------------------------------------------------------------------
__global__ void k_lin3f(const float* __restrict__ out2, const float* __restrict__ W3,
                        const float* __restrict__ as3, const float* __restrict__ ad3,
                        float* __restrict__ h3, float* __restrict__ als,
                        float* __restrict__ ald, int n) {
    int node = blockIdx.x * blockDim.x + threadIdx.x;
    if (node >= n) return;
    float a0 = 0.f, a1 = 0.f, a2 = 0.f, a3 = 0.f;
    #pragma unroll 1
    for (int c = 0; c < 54; ++c) {
        float t = fmaxf(out2[node * 54 + c], 0.f);
        a0 += t * W3[c * 4 + 0];
        a1 += t * W3[c * 4 + 1];
        a2 += t * W3[c * 4 + 2];
        a3 += t * W3[c * 4 + 3];
    }
    h3[node * 4 + 0] = a0; h3[node * 4 + 1] = a1;
    h3[node * 4 + 2] = a2; h3[node * 4 + 3] = a3;
    als[node] = a0 * as3[0] + a1 * as3[1] + a2 * as3[2] + a3 * as3[3];
    ald[node] = a0 * ad3[0] + a1 * ad3[1] + a2 * ad3[2] + a3 * ad3[3];
}

// ---------------------------------------------------------------------------
// Layer 3 aggregation fused with global max pool. Max-free 2-pass.
// Pass C: 64 edge slots; each lane loads a full float4 h3 row + its weight.
// ---------------------------------------------------------------------------
__global__ void k_agg3pool(const int* __restrict__ rp, const int* __restrict__ srcs,
                           const float* __restrict__ h3, const float* __restrict__ als,
                           const float* __restrict__ ald, float* __restrict__ wv,
                           const float* __restrict__ b3, const int* __restrict__ batch,
                           unsigned* __restrict__ genc, int n) {
    int wid = threadIdx.x >> 6, lane = threadIdx.x & 63;
    int node = blockIdx.x * (blockDim.x >> 6) + wid;
    if (node >= n) return;
    int beg = rp[node], end = rp[node + 1];
    float aldv = ald[node];

    float ss = 0.f;
    for (int i = beg + lane; i < end; i += 64) {
        float e = __expf(leaky(als[srcs[i]] + aldv));
        wv[i] = e;
        ss += e;
    }
    #pragma unroll
    for (int off = 32; off; off >>= 1) ss += __shfl_xor(ss, off, 64);
    float inv = 1.f / (ss + 1e-16f);

    float ax = 0.f, ay = 0.f, az = 0.f, aw = 0.f;
    const float4* h4 = (const float4*)h3;
    for (int i = beg + lane; i < end; i += 64) {
        float w = wv[i];
        float4 v = h4[srcs[i]];
        ax += v.x * w; ay += v.y * w; az += v.z * w; aw += v.w * w;
    }
    #pragma unroll
    for (int off = 32; off; off >>= 1) {
        ax += __shfl_xor(ax, off, 64);
        ay += __shfl_xor(ay, off, 64);
        az += __shfl_xor(az, off, 64);
        aw += __shfl_xor(aw, off, 64);
    }
    if (lane < 4) {
        float v = (lane == 0) ? ax : (lane == 1) ? ay : (lane == 2) ? az : aw;
        atomicMax(&genc[batch[node] * 4 + lane], f2mono(v * inv + b3[lane]));
    }
}

__global__ void k_final(const unsigned* __restrict__ genc, float* __restrict__ out) {
    int g = threadIdx.x;   // 256 threads, one per graph
    float v[4];
    #pragma unroll
    for (int c = 0; c < 4; ++c) v[c] = mono2f(genc[g * 4 + c]);
    float mx = fmaxf(fmaxf(v[0], v[1]), fmaxf(v[2], v[3]));
    float s = 0.f;
    #pragma unroll
    for (int c = 0; c < 4; ++c) s += expf(v[c] - mx);
    float l = mx + logf(s);
    #pragma unroll
    for (int c = 0; c < 4; ++c) out[g * 4 + c] = v[c] - l;
}

// ---------------------------------------------------------------------------
extern "C" void kernel_launch(void* const* d_in, const int* in_sizes, int n_in,
                              void* d_out, int out_size, void* d_ws, size_t ws_size,
                              hipStream_t stream) {
    const float* x     = (const float*)d_in[0];
    const int*   ei    = (const int*)d_in[1];     // [2, E] flat
    const int*   batch = (const int*)d_in[2];
    const float* W1    = (const float*)d_in[3];
    const float* as1   = (const float*)d_in[4];
    const float* ad1   = (const float*)d_in[5];
    const float* b1    = (const float*)d_in[6];
    const float* W2    = (const float*)d_in[7];
    const float* as2   = (const float*)d_in[8];
    const float* ad2   = (const float*)d_in[9];
    const float* b2    = (const float*)d_in[10];
    const float* W3    = (const float*)d_in[11];
    const float* as3   = (const float*)d_in[12];
    const float* ad3   = (const float*)d_in[13];
    const float* b3    = (const float*)d_in[14];
    float* out = (float*)d_out;

    const int* src = ei;
    const int* dst = ei + N_EDGES;

    char* base = (char*)d_ws;
    size_t off = 0;
    auto alloc = [&](size_t bytes) -> char* {
        char* p = base + off;
        off = (off + bytes + 255) & ~(size_t)255;
        return p;
    };
    int*      counts  = (int*)alloc((size_t)N_NODES * 4);
    int*      fill    = (int*)alloc((size_t)N_NODES * 4);
    int*      row_ptr = (int*)alloc((size_t)(N_NODES + 1) * 4);
    int*      srcs    = (int*)alloc((size_t)E_TOT * 4);
    int*      bsum    = (int*)alloc(512 * 4);
    int*      boff    = (int*)alloc(512 * 4);
    float*    als     = (float*)alloc((size_t)N_NODES * 3 * 4);
    float*    ald     = (float*)alloc((size_t)N_NODES * 3 * 4);
    float*    wv      = (float*)alloc((size_t)E_TOT * 3 * 4);   // unnormalized edge weights
    float*    aggx    = (float*)alloc((size_t)N_NODES * 27 * 4);
    float*    h2      = (float*)alloc((size_t)N_NODES * 54 * 4);
    float*    out2    = (float*)alloc((size_t)N_NODES * 54 * 4);
    float*    h3      = (float*)alloc((size_t)N_NODES * 4 * 4);
    unsigned* genc    = (unsigned*)alloc((size_t)N_GRAPHS * 4 * 4);
    if (off > ws_size) return;

    const int TB = 256;
    const int nb_n  = (N_NODES + TB - 1) / TB;      // 313
    const int nb_et = (E_TOT + TB - 1) / TB;
    const int nb_w  = (N_NODES + 3) / 4;            // 4 node-waves per block

    // --- CSR build + layer-1 pre-pass (fused into scan finalize) ---
    k_init<<<nb_n, TB, 0, stream>>>(counts, fill, genc);
    k_hist<<<nb_et, TB, 0, stream>>>(dst, counts);
    k_scan_block<<<nb_n, SCAN_B, 0, stream>>>(counts, row_ptr, bsum, N_NODES);
    k_scan_tops<<<1, 512, 0, stream>>>(bsum, boff, nb_n);
    k_scan_add_pre1<<<nb_n, TB, 0, stream>>>(row_ptr, boff, x, W1, as1, ad1, als, ald, N_NODES);
    k_scatter<<<nb_et, TB, 0, stream>>>(src, dst, row_ptr, fill, srcs);

    // --- layer 1 (factorized: aggregate x, multiply by W1 inside lin2f) ---
    k_agg1x<<<nb_w, TB, 0, stream>>>(row_ptr, srcs, x, als, ald, wv, aggx, N_NODES);

    // --- layer 2 ---
    k_lin2f<<<nb_n, TB, 0, stream>>>(aggx, W1, b1, W2, as2, ad2, h2, als, ald, N_NODES);
    k_agg2<<<nb_w, TB, 0, stream>>>(row_ptr, srcs, h2, als, ald, wv, b2, out2, N_NODES);

    // --- layer 3 + pool ---
    k_lin3f<<<nb_n, TB, 0, stream>>>(out2, W3, as3, ad3, h3, als, ald, N_NODES);
    k_agg3pool<<<nb_w, TB, 0, stream>>>(row_ptr, srcs, h3, als, ald, wv, b3, batch, genc, N_NODES);
    k_final<<<1, N_GRAPHS, 0, stream>>>(genc, out);
}

// Round 7
// 546.992 us; speedup vs baseline: 2.2394x; 1.0431x over previous
//
#include <hip/hip_runtime.h>
#include <hip/hip_bf16.h>

#define N_NODES 80000
#define N_EDGES 1280000
#define E_TOT   (N_EDGES + N_NODES)   // + self loops
#define N_GRAPHS 256
#define NEG_SLOPE 0.2f

// leaky_relu(a) = max(a, 0.2*a)  (valid since 0<slope<1)
__device__ __forceinline__ float leaky(float a) { return fmaxf(a, NEG_SLOPE * a); }

// pick arr[h] with runtime h from a static-unrolled register array (no scratch)
template <int H>
__device__ __forceinline__ float pick(const float (&arr)[H], int h) {
    float r = arr[0];
    #pragma unroll
    for (int j = 1; j < H; ++j) r = (h == j) ? arr[j] : r;
    return r;
}

__device__ __forceinline__ unsigned f2mono(float f) {
    unsigned u = __float_as_uint(f);
    return u ^ ((u >> 31) ? 0xFFFFFFFFu : 0x80000000u);
}
__device__ __forceinline__ float mono2f(unsigned u) {
    u = (u & 0x80000000u) ? (u ^ 0x80000000u) : ~u;
    return __uint_as_float(u);
}

// ---------------------------------------------------------------------------
// Init: zero counts/fill, init pool accumulators
// ---------------------------------------------------------------------------
__global__ void k_init(int* __restrict__ counts, int* __restrict__ fill,
                       unsigned* __restrict__ genc) {
    int i = blockIdx.x * blockDim.x + threadIdx.x;
    if (i < N_NODES) { counts[i] = 0; fill[i] = 0; }
    if (i < N_GRAPHS * 4) genc[i] = f2mono(-1e9f);
}

// ---------------------------------------------------------------------------
// CSR build (by dst). Self-loops appended as virtual edges i in [E, E+N).
// ---------------------------------------------------------------------------
__global__ void k_hist(const int* __restrict__ dst, int* __restrict__ counts) {
    int i = blockIdx.x * blockDim.x + threadIdx.x;
    if (i >= E_TOT) return;
    int d = (i < N_EDGES) ? dst[i] : (i - N_EDGES);
    atomicAdd(&counts[d], 1);
}

#define SCAN_B 256
__global__ void k_scan_block(const int* __restrict__ counts, int* __restrict__ rp,
                             int* __restrict__ bsum, int n) {
    __shared__ int sa[SCAN_B], sb[SCAN_B];
    int tid = threadIdx.x;
    int gi = blockIdx.x * SCAN_B + tid;
    int v = (gi < n) ? counts[gi] : 0;
    sa[tid] = v;
    __syncthreads();
    int* cur = sa; int* nxt = sb;
    #pragma unroll
    for (int d = 1; d < SCAN_B; d <<= 1) {
        int t = cur[tid];
        if (tid >= d) t += cur[tid - d];
        nxt[tid] = t;
        __syncthreads();
        int* tmp = cur; cur = nxt; nxt = tmp;
    }
    if (gi < n) rp[gi] = cur[tid] - v;            // block-local exclusive
    if (tid == SCAN_B - 1) bsum[blockIdx.x] = cur[tid];
}

__global__ void k_scan_tops(const int* __restrict__ bsum, int* __restrict__ boff, int nb) {
    __shared__ int sa[512], sb[512];
    int tid = threadIdx.x;
    int v = (tid < nb) ? bsum[tid] : 0;
    sa[tid] = v;
    __syncthreads();
    int* cur = sa; int* nxt = sb;
    #pragma unroll
    for (int d = 1; d < 512; d <<= 1) {
        int t = cur[tid];
        if (tid >= d) t += cur[tid - d];
        nxt[tid] = t;
        __syncthreads();
        int* tmp = cur; cur = nxt; nxt = tmp;
    }
    if (tid < nb) boff[tid] = cur[tid] - v;
}

// scan finalize FUSED with layer-1 pre-pass (same 313x256 grid):
// rp[gi] += boff[block]; als1/ald1 from x via projected 3x9 matrices
// ps[h][k] = sum_c W1[k, h*45+c] * a_src[h,c]   (h1 never materialized)
__global__ void k_scan_add_pre1(int* __restrict__ rp, const int* __restrict__ boff,
                                const float* __restrict__ x, const float* __restrict__ W1,
                                const float* __restrict__ as1, const float* __restrict__ ad1,
                                float* __restrict__ als, float* __restrict__ ald, int n) {
    __shared__ float ps[27], pd[27];
    int t = threadIdx.x;
    int gi = blockIdx.x * blockDim.x + t;
    if (gi < n) rp[gi] += boff[blockIdx.x];
    if (gi == 0) rp[n] = E_TOT;
    if (t < 27) {
        int h = t / 9, k = t % 9;
        float s = 0.f, d = 0.f;
        for (int c = 0; c < 45; ++c) {
            float w = W1[k * 135 + h * 45 + c];
            s += w * as1[h * 45 + c];
            d += w * ad1[h * 45 + c];
        }
        ps[t] = s; pd[t] = d;
    }
    __syncthreads();
    if (gi >= n) return;
    float xr[9];
    #pragma unroll
    for (int k = 0; k < 9; ++k) xr[k] = x[gi * 9 + k];
    #pragma unroll
    for (int h = 0; h < 3; ++h) {
        float s = 0.f, d = 0.f;
        #pragma unroll
        for (int k = 0; k < 9; ++k) { s += xr[k] * ps[h * 9 + k]; d += xr[k] * pd[h * 9 + k]; }
        als[gi * 3 + h] = s;
        ald[gi * 3 + h] = d;
    }
}

__global__ void k_scatter(const int* __restrict__ src, const int* __restrict__ dst,
                          const int* __restrict__ rp, int* __restrict__ fill,
                          int* __restrict__ srcs) {
    int i = blockIdx.x * blockDim.x + threadIdx.x;
    if (i >= E_TOT) return;
    int s, d;
    if (i < N_EDGES) { s = src[i]; d = dst[i]; }
    else             { s = i - N_EDGES; d = s; }
    int pos = rp[d] + atomicAdd(&fill[d], 1);
    srcs[pos] = s;
}

// ---------------------------------------------------------------------------
// Layer 1 aggregation over x (factorized): aggx[n, h*9+k] = (1/s_h) sum_e e_h(i) x[src,k]
// Max-free softmax. Pass B: 3 exp/edge -> wv + sum. Pass C: 2 slots x 27 ch,
// UNROLLED x8 (16 edges in flight; deg~17 fits one unrolled batch per slot).
// ---------------------------------------------------------------------------
__global__ void k_agg1x(const int* __restrict__ rp, const int* __restrict__ srcs,
                        const float* __restrict__ x, const float* __restrict__ als,
                        const float* __restrict__ ald, float* __restrict__ wv,
                        float* __restrict__ aggx, int n) {
    int wid = threadIdx.x >> 6, lane = threadIdx.x & 63;
    int node = blockIdx.x * (blockDim.x >> 6) + wid;
    if (node >= n) return;
    int beg = rp[node], end = rp[node + 1];

    float aldv[3];
    #pragma unroll
    for (int h = 0; h < 3; ++h) aldv[h] = ald[node * 3 + h];

    // pass B: unnormalized weights + sum
    float ss[3] = {0.f, 0.f, 0.f};
    for (int i = beg + lane; i < end; i += 64) {
        int s = srcs[i];
        #pragma unroll
        for (int h = 0; h < 3; ++h) {
            float e = __expf(leaky(als[s * 3 + h] + aldv[h]));
            wv[i * 3 + h] = e;
            ss[h] += e;
        }
    }
    #pragma unroll
    for (int h = 0; h < 3; ++h) {
        #pragma unroll
        for (int off = 32; off; off >>= 1) ss[h] += __shfl_xor(ss[h], off, 64);
    }
    float inv[3];
    #pragma unroll
    for (int h = 0; h < 3; ++h) inv[h] = 1.f / (ss[h] + 1e-16f);

    // pass C: li in [0,27): (h, k); two edge slots (es = lane>>5), unroll x8
    int es = lane >> 5, li = lane & 31;
    int lic = li < 27 ? li : 26;     // clamp keeps loads in-bounds, no branch
    int hh = lic / 9;
    int kk = lic % 9;
    float invh = pick(inv, hh);

    float acc = 0.f;
    int i = beg + es;
    for (; i + 14 < end; i += 16) {   // 8 edges per slot in flight
        int s0 = srcs[i],      s1 = srcs[i + 2],  s2 = srcs[i + 4],  s3 = srcs[i + 6];
        int s4 = srcs[i + 8],  s5 = srcs[i + 10], s6 = srcs[i + 12], s7 = srcs[i + 14];
        float w0 = wv[i * 3 + hh],        w1 = wv[(i + 2) * 3 + hh];
        float w2 = wv[(i + 4) * 3 + hh],  w3 = wv[(i + 6) * 3 + hh];
        float w4 = wv[(i + 8) * 3 + hh],  w5 = wv[(i + 10) * 3 + hh];
        float w6 = wv[(i + 12) * 3 + hh], w7 = wv[(i + 14) * 3 + hh];
        float x0 = x[s0 * 9 + kk], x1 = x[s1 * 9 + kk];
        float x2 = x[s2 * 9 + kk], x3 = x[s3 * 9 + kk];
        float x4 = x[s4 * 9 + kk], x5 = x[s5 * 9 + kk];
        float x6 = x[s6 * 9 + kk], x7 = x[s7 * 9 + kk];
        acc += x0 * w0 + x1 * w1 + x2 * w2 + x3 * w3
             + x4 * w4 + x5 * w5 + x6 * w6 + x7 * w7;
    }
    for (; i < end; i += 2) {
        acc += x[srcs[i] * 9 + kk] * wv[i * 3 + hh];
    }
    acc += __shfl_xor(acc, 32, 64);
    if (lane < 27) aggx[node * 27 + lane] = acc * invh;
}

// ---------------------------------------------------------------------------
// Fused: out1 = aggx @ W1 + b1 -> ReLU -> h2 = out1 @ W2 ; als2/ald2 dots.
// ---------------------------------------------------------------------------
__global__ void k_lin2f(const float* __restrict__ aggx, const float* __restrict__ W1,
                        const float* __restrict__ b1, const float* __restrict__ W2,
                        const float* __restrict__ as2, const float* __restrict__ ad2,
                        float* __restrict__ h2, float* __restrict__ als,
                        float* __restrict__ ald, int n) {
    int node = blockIdx.x * blockDim.x + threadIdx.x;
    if (node >= n) return;
    float ax[27];
    #pragma unroll
    for (int j = 0; j < 27; ++j) ax[j] = aggx[node * 27 + j];
    float acc[54];
    #pragma unroll
    for (int c = 0; c < 54; ++c) acc[c] = 0.f;
    #pragma unroll
    for (int h = 0; h < 3; ++h) {          // must be unrolled: ax[] static idx
        #pragma unroll 1
        for (int c0 = 0; c0 < 45; ++c0) {
            int col = h * 45 + c0;
            float t = b1[col];
            #pragma unroll
            for (int k = 0; k < 9; ++k) t += ax[h * 9 + k] * W1[k * 135 + col];
            t = fmaxf(t, 0.f);             // ReLU between layers
            #pragma unroll
            for (int cc = 0; cc < 54; ++cc) acc[cc] += t * W2[col * 54 + cc];
        }
    }
    float as_[3] = {0.f, 0.f, 0.f}, ad_[3] = {0.f, 0.f, 0.f};
    #pragma unroll
    for (int c = 0; c < 54; ++c) {
        h2[node * 54 + c] = acc[c];
        as_[c / 18] += acc[c] * as2[c];
        ad_[c / 18] += acc[c] * ad2[c];
    }
    #pragma unroll
    for (int h = 0; h < 3; ++h) { als[node * 3 + h] = as_[h]; ald[node * 3 + h] = ad_[h]; }
}

// ---------------------------------------------------------------------------
// Layer 2 aggregation: max-free 2-pass; pass C = 2 slots x 27 float2, x8 unroll.
// ---------------------------------------------------------------------------
__global__ void k_agg2(const int* __restrict__ rp, const int* __restrict__ srcs,
                       const float* __restrict__ h, const float* __restrict__ als,
                       const float* __restrict__ ald, float* __restrict__ wv,
                       const float* __restrict__ bias, float* __restrict__ out, int n) {
    int wid = threadIdx.x >> 6, lane = threadIdx.x & 63;
    int node = blockIdx.x * (blockDim.x >> 6) + wid;
    if (node >= n) return;
    int beg = rp[node], end = rp[node + 1];

    float aldv[3];
    #pragma unroll
    for (int hh = 0; hh < 3; ++hh) aldv[hh] = ald[node * 3 + hh];

    float ss[3] = {0.f, 0.f, 0.f};
    for (int i = beg + lane; i < end; i += 64) {
        int s = srcs[i];
        #pragma unroll
        for (int hh = 0; hh < 3; ++hh) {
            float e = __expf(leaky(als[s * 3 + hh] + aldv[hh]));
            wv[i * 3 + hh] = e;
            ss[hh] += e;
        }
    }
    #pragma unroll
    for (int hh = 0; hh < 3; ++hh) {
        #pragma unroll
        for (int off = 32; off; off >>= 1) ss[hh] += __shfl_xor(ss[hh], off, 64);
    }
    float inv[3];
    #pragma unroll
    for (int hh = 0; hh < 3; ++hh) inv[hh] = 1.f / (ss[hh] + 1e-16f);

    // pass C: lane -> (edge slot es, float2-channel lic); pair never straddles heads
    int es = lane >> 5, li = lane & 31;
    bool act = li < 27;
    int lic = act ? li : 26;
    int hh = lic / 9;
    float invh = pick(inv, hh);
    const float2* hv = (const float2*)h;

    float accx = 0.f, accy = 0.f;
    int i = beg + es;
    for (; i + 14 < end; i += 16) {   // 8 edges per slot in flight
        int s0 = srcs[i],      s1 = srcs[i + 2],  s2 = srcs[i + 4],  s3 = srcs[i + 6];
        int s4 = srcs[i + 8],  s5 = srcs[i + 10], s6 = srcs[i + 12], s7 = srcs[i + 14];
        float w0 = wv[i * 3 + hh],        w1 = wv[(i + 2) * 3 + hh];
        float w2 = wv[(i + 4) * 3 + hh],  w3 = wv[(i + 6) * 3 + hh];
        float w4 = wv[(i + 8) * 3 + hh],  w5 = wv[(i + 10) * 3 + hh];
        float w6 = wv[(i + 12) * 3 + hh], w7 = wv[(i + 14) * 3 + hh];
        float2 v0 = hv[s0 * 27 + lic], v1 = hv[s1 * 27 + lic];
        float2 v2 = hv[s2 * 27 + lic], v3 = hv[s3 * 27 + lic];
        float2 v4 = hv[s4 * 27 + lic], v5 = hv[s5 * 27 + lic];
        float2 v6 = hv[s6 * 27 + lic], v7 = hv[s7 * 27 + lic];
        accx += v0.x * w0 + v1.x * w1 + v2.x * w2 + v3.x * w3
              + v4.x * w4 + v5.x * w5 + v6.x * w6 + v7.x * w7;
        accy += v0.y * w0 + v1.y * w1 + v2.y * w2 + v3.y * w3
              + v4.y * w4 + v5.y * w5 + v6.y * w6 + v7.y * w7;
    }
    for (; i < end; i += 2) {
        float w = wv[i * 3 + hh];
        float2 v = hv[srcs[i] * 27 + lic];
        accx += v.x * w;
        accy += v.y * w;
    }
    accx += __shfl_xor(accx, 32, 64);
    accy += __shfl_xor(accy, 32, 64);
    if (act && es == 0) {
        float2 b = ((const float2*)bias)[li];
        float2 o; o.x = accx * invh + b.x; o.y = accy * invh + b.y;
        ((float2*)out)[(long)node * 27 + li] = o;
    }
}

// ---------------------------------------------------------------------------
// Layer 3 linear: relu(out2) @ W3 -> h3[4]; als3/ald3 dots.
// ---------------------------------------------------------------------------
__global__ void k_lin3f(const float* __restrict__ out2, const float* __restrict__ W3,
                        const float* __restrict__ as3, const float* __restrict__ ad3,
                        float* __restrict__ h3, float* __restrict__ als,
                        float* __restrict__ ald, int n) {
    int node = blockIdx.x * blockDim.x + threadIdx.x;
    if (node >= n) return;
    float a0 = 0.f, a1 = 0.f, a2 = 0.f, a3 = 0.f;
    #pragma unroll 1
    for (int c = 0; c < 54; ++c) {
        float t = fmaxf(out2[node * 54 + c], 0.f);
        a0 += t * W3[c * 4 + 0];
        a1 += t * W3[c * 4 + 1];
        a2 += t * W3[c * 4 + 2];
        a3 += t * W3[c * 4 + 3];
    }
    h3[node * 4 + 0] = a0; h3[node * 4 + 1] = a1;
    h3[node * 4 + 2] = a2; h3[node * 4 + 3] = a3;
    als[node] = a0 * as3[0] + a1 * as3[1] + a2 * as3[2] + a3 * as3[3];
    ald[node] = a0 * ad3[0] + a1 * ad3[1] + a2 * ad3[2] + a3 * ad3[3];
}

// ---------------------------------------------------------------------------
// Layer 3 aggregation fused with global max pool. 16 LANES PER NODE
// (16 nodes per 256-block: 4x wave efficiency at deg~17). Max-free softmax,
// exp recomputed in pass C (no wv round-trip; VALU is idle anyway).
// ---------------------------------------------------------------------------
__global__ void k_agg3pool(const int* __restrict__ rp, const int* __restrict__ srcs,
                           const float* __restrict__ h3, const float* __restrict__ als,
                           const float* __restrict__ ald, const float* __restrict__ b3,
                           const int* __restrict__ batch, unsigned* __restrict__ genc, int n) {
    int sub = threadIdx.x & 15;
    int node = blockIdx.x * (blockDim.x >> 4) + (threadIdx.x >> 4);
    if (node >= n) return;
    int beg = rp[node], end = rp[node + 1];
    float aldv = ald[node];

    float ss = 0.f;
    for (int i = beg + sub; i < end; i += 16)
        ss += __expf(leaky(als[srcs[i]] + aldv));
    #pragma unroll
    for (int off = 8; off; off >>= 1) ss += __shfl_xor(ss, off, 64);
    float inv = 1.f / (ss + 1e-16f);

    float ax = 0.f, ay = 0.f, az = 0.f, aw = 0.f;
    const float4* h4 = (const float4*)h3;
    for (int i = beg + sub; i < end; i += 16) {
        int s = srcs[i];
        float w = __expf(leaky(als[s] + aldv));
        float4 v = h4[s];
        ax += v.x * w; ay += v.y * w; az += v.z * w; aw += v.w * w;
    }
    #pragma unroll
    for (int off = 8; off; off >>= 1) {
        ax += __shfl_xor(ax, off, 64);
        ay += __shfl_xor(ay, off, 64);
        az += __shfl_xor(az, off, 64);
        aw += __shfl_xor(aw, off, 64);
    }
    if (sub < 4) {
        float v = (sub == 0) ? ax : (sub == 1) ? ay : (sub == 2) ? az : aw;
        atomicMax(&genc[batch[node] * 4 + sub], f2mono(v * inv + b3[sub]));
    }
}

__global__ void k_final(const unsigned* __restrict__ genc, float* __restrict__ out) {
    int g = threadIdx.x;   // 256 threads, one per graph
    float v[4];
    #pragma unroll
    for (int c = 0; c < 4; ++c) v[c] = mono2f(genc[g * 4 + c]);
    float mx = fmaxf(fmaxf(v[0], v[1]), fmaxf(v[2], v[3]));
    float s = 0.f;
    #pragma unroll
    for (int c = 0; c < 4; ++c) s += expf(v[c] - mx);
    float l = mx + logf(s);
    #pragma unroll
    for (int c = 0; c < 4; ++c) out[g * 4 + c] = v[c] - l;
}

// ---------------------------------------------------------------------------
extern "C" void kernel_launch(void* const* d_in, const int* in_sizes, int n_in,
                              void* d_out, int out_size, void* d_ws, size_t ws_size,
                              hipStream_t stream) {
    const float* x     = (const float*)d_in[0];
    const int*   ei    = (const int*)d_in[1];     // [2, E] flat
    const int*   batch = (const int*)d_in[2];
    const float* W1    = (const float*)d_in[3];
    const float* as1   = (const float*)d_in[4];
    const float* ad1   = (const float*)d_in[5];
    const float* b1    = (const float*)d_in[6];
    const float* W2    = (const float*)d_in[7];
    const float* as2   = (const float*)d_in[8];
    const float* ad2   = (const float*)d_in[9];
    const float* b2    = (const float*)d_in[10];
    const float* W3    = (const float*)d_in[11];
    const float* as3   = (const float*)d_in[12];
    const float* ad3   = (const float*)d_in[13];
    const float* b3    = (const float*)d_in[14];
    float* out = (float*)d_out;

    const int* src = ei;
    const int* dst = ei + N_EDGES;

    char* base = (char*)d_ws;
    size_t off = 0;
    auto alloc = [&](size_t bytes) -> char* {
        char* p = base + off;
        off = (off + bytes + 255) & ~(size_t)255;
        return p;
    };
    int*      counts  = (int*)alloc((size_t)N_NODES * 4);
    int*      fill    = (int*)alloc((size_t)N_NODES * 4);
    int*      row_ptr = (int*)alloc((size_t)(N_NODES + 1) * 4);
    int*      srcs    = (int*)alloc((size_t)E_TOT * 4);
    int*      bsum    = (int*)alloc(512 * 4);
    int*      boff    = (int*)alloc(512 * 4);
    float*    als     = (float*)alloc((size_t)N_NODES * 3 * 4);
    float*    ald     = (float*)alloc((size_t)N_NODES * 3 * 4);
    float*    wv      = (float*)alloc((size_t)E_TOT * 3 * 4);   // unnormalized edge weights
    float*    aggx    = (float*)alloc((size_t)N_NODES * 27 * 4);
    float*    h2      = (float*)alloc((size_t)N_NODES * 54 * 4);
    float*    out2    = (float*)alloc((size_t)N_NODES * 54 * 4);
    float*    h3      = (float*)alloc((size_t)N_NODES * 4 * 4);
    unsigned* genc    = (unsigned*)alloc((size_t)N_GRAPHS * 4 * 4);
    if (off > ws_size) return;

    const int TB = 256;
    const int nb_n  = (N_NODES + TB - 1) / TB;      // 313
    const int nb_et = (E_TOT + TB - 1) / TB;
    const int nb_w  = (N_NODES + 3) / 4;            // 4 node-waves per block
    const int nb_16 = (N_NODES + 15) / 16;          // 16 nodes per block (16 lanes each)

    // --- CSR build + layer-1 pre-pass (fused into scan finalize) ---
    k_init<<<nb_n, TB, 0, stream>>>(counts, fill, genc);
    k_hist<<<nb_et, TB, 0, stream>>>(dst, counts);
    k_scan_block<<<nb_n, SCAN_B, 0, stream>>>(counts, row_ptr, bsum, N_NODES);
    k_scan_tops<<<1, 512, 0, stream>>>(bsum, boff, nb_n);
    k_scan_add_pre1<<<nb_n, TB, 0, stream>>>(row_ptr, boff, x, W1, as1, ad1, als, ald, N_NODES);
    k_scatter<<<nb_et, TB, 0, stream>>>(src, dst, row_ptr, fill, srcs);

    // --- layer 1 (factorized: aggregate x, multiply by W1 inside lin2f) ---
    k_agg1x<<<nb_w, TB, 0, stream>>>(row_ptr, srcs, x, als, ald, wv, aggx, N_NODES);

    // --- layer 2 ---
    k_lin2f<<<nb_n, TB, 0, stream>>>(aggx, W1, b1, W2, as2, ad2, h2, als, ald, N_NODES);
    k_agg2<<<nb_w, TB, 0, stream>>>(row_ptr, srcs, h2, als, ald, wv, b2, out2, N_NODES);

    // --- layer 3 + pool ---
    k_lin3f<<<nb_n, TB, 0, stream>>>(out2, W3, as3, ad3, h3, als, ald, N_NODES);
    k_agg3pool<<<nb_16, TB, 0, stream>>>(row_ptr, srcs, h3, als, ald, b3, batch, genc, N_NODES);
    k_final<<<1, N_GRAPHS, 0, stream>>>(genc, out);
}

// Round 9
// 478.849 us; speedup vs baseline: 2.5581x; 1.1423x over previous
//
#include <hip/hip_runtime.h>
#include <hip/hip_bf16.h>
#include <hip/hip_fp16.h>

#define N_NODES 80000
#define N_EDGES 1280000
#define E_TOT   (N_EDGES + N_NODES)   // + self loops
#define N_GRAPHS 256
#define NEG_SLOPE 0.2f

// leaky_relu(a) = max(a, 0.2*a)  (valid since 0<slope<1)
__device__ __forceinline__ float leaky(float a) { return fmaxf(a, NEG_SLOPE * a); }

// pick arr[h] with runtime h from a static-unrolled register array (no scratch)
template <int H>
__device__ __forceinline__ float pick(const float (&arr)[H], int h) {
    float r = arr[0];
    #pragma unroll
    for (int j = 1; j < H; ++j) r = (h == j) ? arr[j] : r;
    return r;
}

__device__ __forceinline__ unsigned f2mono(float f) {
    unsigned u = __float_as_uint(f);
    return u ^ ((u >> 31) ? 0xFFFFFFFFu : 0x80000000u);
}
__device__ __forceinline__ float mono2f(unsigned u) {
    u = (u & 0x80000000u) ? (u ^ 0x80000000u) : ~u;
    return __uint_as_float(u);
}

// ---------------------------------------------------------------------------
// Init: counts=1 (self-loop), init pool accumulators
// ---------------------------------------------------------------------------
__global__ void k_init(int* __restrict__ counts, unsigned* __restrict__ genc) {
    int i = blockIdx.x * blockDim.x + threadIdx.x;
    if (i < N_NODES) counts[i] = 1;
    if (i < N_GRAPHS * 4) genc[i] = f2mono(-1e9f);
}

// ---------------------------------------------------------------------------
// CSR build (by dst). hist also records each edge's within-node rank, so
// scatter needs NO atomics. Self-loop owns rank 0 (counts init = 1).
// ---------------------------------------------------------------------------
__global__ void k_hist(const int* __restrict__ dst, int* __restrict__ counts,
                       int* __restrict__ erank) {
    int i = blockIdx.x * blockDim.x + threadIdx.x;
    if (i >= N_EDGES) return;
    erank[i] = atomicAdd(&counts[dst[i]], 1);
}

#define SCAN_B 256
__global__ void k_scan_block(const int* __restrict__ counts, int* __restrict__ rp,
                             int* __restrict__ bsum, int n) {
    __shared__ int sa[SCAN_B], sb[SCAN_B];
    int tid = threadIdx.x;
    int gi = blockIdx.x * SCAN_B + tid;
    int v = (gi < n) ? counts[gi] : 0;
    sa[tid] = v;
    __syncthreads();
    int* cur = sa; int* nxt = sb;
    #pragma unroll
    for (int d = 1; d < SCAN_B; d <<= 1) {
        int t = cur[tid];
        if (tid >= d) t += cur[tid - d];
        nxt[tid] = t;
        __syncthreads();
        int* tmp = cur; cur = nxt; nxt = tmp;
    }
    if (gi < n) rp[gi] = cur[tid] - v;            // block-local exclusive
    if (tid == SCAN_B - 1) bsum[blockIdx.x] = cur[tid];
}

__global__ void k_scan_tops(const int* __restrict__ bsum, int* __restrict__ boff, int nb) {
    __shared__ int sa[512], sb[512];
    int tid = threadIdx.x;
    int v = (tid < nb) ? bsum[tid] : 0;
    sa[tid] = v;
    __syncthreads();
    int* cur = sa; int* nxt = sb;
    #pragma unroll
    for (int d = 1; d < 512; d <<= 1) {
        int t = cur[tid];
        if (tid >= d) t += cur[tid - d];
        nxt[tid] = t;
        __syncthreads();
        int* tmp = cur; cur = nxt; nxt = tmp;
    }
    if (tid < nb) boff[tid] = cur[tid] - v;
}

// scan finalize FUSED with (a) self-loop scatter into srcs, (b) layer-1
// pre-pass: als1/ald1 from x via projected 3x9 matrices.
__global__ void k_scan_add_pre1(int* __restrict__ rp, const int* __restrict__ boff,
                                int* __restrict__ srcs,
                                const float* __restrict__ x, const float* __restrict__ W1,
                                const float* __restrict__ as1, const float* __restrict__ ad1,
                                float* __restrict__ als, float* __restrict__ ald, int n) {
    __shared__ float ps[27], pd[27];
    int t = threadIdx.x;
    int gi = blockIdx.x * blockDim.x + t;
    if (gi < n) {
        int r = rp[gi] + boff[blockIdx.x];
        rp[gi] = r;
        srcs[r] = gi;                 // self-loop at rank 0
    }
    if (gi == 0) rp[n] = E_TOT;
    if (t < 27) {
        int h = t / 9, k = t % 9;
        float s = 0.f, d = 0.f;
        for (int c = 0; c < 45; ++c) {
            float w = W1[k * 135 + h * 45 + c];
            s += w * as1[h * 45 + c];
            d += w * ad1[h * 45 + c];
        }
        ps[t] = s; pd[t] = d;
    }
    __syncthreads();
    if (gi >= n) return;
    float xr[9];
    #pragma unroll
    for (int k = 0; k < 9; ++k) xr[k] = x[gi * 9 + k];
    #pragma unroll
    for (int h = 0; h < 3; ++h) {
        float s = 0.f, d = 0.f;
        #pragma unroll
        for (int k = 0; k < 9; ++k) { s += xr[k] * ps[h * 9 + k]; d += xr[k] * pd[h * 9 + k]; }
        als[gi * 3 + h] = s;
        ald[gi * 3 + h] = d;
    }
}

// atomic-free scatter: pos = rp[dst] + erank
__global__ void k_scatter(const int* __restrict__ src, const int* __restrict__ dst,
                          const int* __restrict__ rp, const int* __restrict__ erank,
                          int* __restrict__ srcs) {
    int i = blockIdx.x * blockDim.x + threadIdx.x;
    if (i >= N_EDGES) return;
    srcs[rp[dst[i]] + erank[i]] = src[i];
}

// ---------------------------------------------------------------------------
// Layer 1 aggregation over x (factorized): aggx[n, h*9+k] = (1/s_h) sum_e e_h(i) x[src,k]
// Max-free softmax. Pass B: 3 exp/edge -> wv + sum. Pass C: 2 slots x 27 ch, x8 unroll.
// ---------------------------------------------------------------------------
__global__ void k_agg1x(const int* __restrict__ rp, const int* __restrict__ srcs,
                        const float* __restrict__ x, const float* __restrict__ als,
                        const float* __restrict__ ald, float* __restrict__ wv,
                        float* __restrict__ aggx, int n) {
    int wid = threadIdx.x >> 6, lane = threadIdx.x & 63;
    int node = blockIdx.x * (blockDim.x >> 6) + wid;
    if (node >= n) return;
    int beg = rp[node], end = rp[node + 1];

    float aldv[3];
    #pragma unroll
    for (int h = 0; h < 3; ++h) aldv[h] = ald[node * 3 + h];

    // pass B: unnormalized weights + sum
    float ss[3] = {0.f, 0.f, 0.f};
    for (int i = beg + lane; i < end; i += 64) {
        int s = srcs[i];
        #pragma unroll
        for (int h = 0; h < 3; ++h) {
            float e = __expf(leaky(als[s * 3 + h] + aldv[h]));
            wv[i * 3 + h] = e;
            ss[h] += e;
        }
    }
    #pragma unroll
    for (int h = 0; h < 3; ++h) {
        #pragma unroll
        for (int off = 32; off; off >>= 1) ss[h] += __shfl_xor(ss[h], off, 64);
    }
    float inv[3];
    #pragma unroll
    for (int h = 0; h < 3; ++h) inv[h] = 1.f / (ss[h] + 1e-16f);

    // pass C: li in [0,27): (h, k); two edge slots (es = lane>>5), unroll x8
    int es = lane >> 5, li = lane & 31;
    int lic = li < 27 ? li : 26;     // clamp keeps loads in-bounds, no branch
    int hh = lic / 9;
    int kk = lic % 9;
    float invh = pick(inv, hh);

    float acc = 0.f;
    int i = beg + es;
    for (; i + 14 < end; i += 16) {   // 8 edges per slot in flight
        int s0 = srcs[i],      s1 = srcs[i + 2],  s2 = srcs[i + 4],  s3 = srcs[i + 6];
        int s4 = srcs[i + 8],  s5 = srcs[i + 10], s6 = srcs[i + 12], s7 = srcs[i + 14];
        float w0 = wv[i * 3 + hh],        w1 = wv[(i + 2) * 3 + hh];
        float w2 = wv[(i + 4) * 3 + hh],  w3 = wv[(i + 6) * 3 + hh];
        float w4 = wv[(i + 8) * 3 + hh],  w5 = wv[(i + 10) * 3 + hh];
        float w6 = wv[(i + 12) * 3 + hh], w7 = wv[(i + 14) * 3 + hh];
        float x0 = x[s0 * 9 + kk], x1 = x[s1 * 9 + kk];
        float x2 = x[s2 * 9 + kk], x3 = x[s3 * 9 + kk];
        float x4 = x[s4 * 9 + kk], x5 = x[s5 * 9 + kk];
        float x6 = x[s6 * 9 + kk], x7 = x[s7 * 9 + kk];
        acc += x0 * w0 + x1 * w1 + x2 * w2 + x3 * w3
             + x4 * w4 + x5 * w5 + x6 * w6 + x7 * w7;
    }
    for (; i < end; i += 2) {
        acc += x[srcs[i] * 9 + kk] * wv[i * 3 + hh];
    }
    acc += __shfl_xor(acc, 32, 64);
    if (lane < 27) aggx[node * 27 + lane] = acc * invh;
}

// ---------------------------------------------------------------------------
// Fused: out1 = aggx @ W1 + b1 -> ReLU -> h2 = out1 @ W2 ; als2/ald2 dots.
// h2 stored as FP16 (halves the layer-2 gather table: 17 -> 8.6 MB).
// ---------------------------------------------------------------------------
__global__ void k_lin2f(const float* __restrict__ aggx, const float* __restrict__ W1,
                        const float* __restrict__ b1, const float* __restrict__ W2,
                        const float* __restrict__ as2, const float* __restrict__ ad2,
                        __half2* __restrict__ h2, float* __restrict__ als,
                        float* __restrict__ ald, int n) {
    int node = blockIdx.x * blockDim.x + threadIdx.x;
    if (node >= n) return;
    float ax[27];
    #pragma unroll
    for (int j = 0; j < 27; ++j) ax[j] = aggx[node * 27 + j];
    float acc[54];
    #pragma unroll
    for (int c = 0; c < 54; ++c) acc[c] = 0.f;
    #pragma unroll
    for (int h = 0; h < 3; ++h) {          // must be unrolled: ax[] static idx
        #pragma unroll 1
        for (int c0 = 0; c0 < 45; ++c0) {
            int col = h * 45 + c0;
            float t = b1[col];
            #pragma unroll
            for (int k = 0; k < 9; ++k) t += ax[h * 9 + k] * W1[k * 135 + col];
            t = fmaxf(t, 0.f);             // ReLU between layers
            #pragma unroll
            for (int cc = 0; cc < 54; ++cc) acc[cc] += t * W2[col * 54 + cc];
        }
    }
    float as_[3] = {0.f, 0.f, 0.f}, ad_[3] = {0.f, 0.f, 0.f};
    #pragma unroll
    for (int c = 0; c < 54; ++c) {
        as_[c / 18] += acc[c] * as2[c];
        ad_[c / 18] += acc[c] * ad2[c];
    }
    #pragma unroll
    for (int j = 0; j < 27; ++j)
        h2[node * 27 + j] = __floats2half2_rn(acc[2 * j], acc[2 * j + 1]);
    #pragma unroll
    for (int h = 0; h < 3; ++h) { als[node * 3 + h] = as_[h]; ald[node * 3 + h] = ad_[h]; }
}

// ---------------------------------------------------------------------------
// Layer 2 aggregation (h2 in FP16) FUSED with layer-3 linear:
// out2 never materialized; epilogue computes h3 = relu(out2)@W3 and als3/ald3
// via a 27-lane cross-lane reduction.
// ---------------------------------------------------------------------------
__global__ void k_agg2(const int* __restrict__ rp, const int* __restrict__ srcs,
                       const __half2* __restrict__ hv, const float* __restrict__ als,
                       const float* __restrict__ ald, float* __restrict__ wv,
                       const float* __restrict__ bias, const float* __restrict__ W3,
                       const float* __restrict__ as3, const float* __restrict__ ad3,
                       float* __restrict__ h3, float* __restrict__ als3,
                       float* __restrict__ ald3, int n) {
    int wid = threadIdx.x >> 6, lane = threadIdx.x & 63;
    int node = blockIdx.x * (blockDim.x >> 6) + wid;
    if (node >= n) return;
    int beg = rp[node], end = rp[node + 1];

    float aldv[3];
    #pragma unroll
    for (int hh = 0; hh < 3; ++hh) aldv[hh] = ald[node * 3 + hh];

    float ss[3] = {0.f, 0.f, 0.f};
    for (int i = beg + lane; i < end; i += 64) {
        int s = srcs[i];
        #pragma unroll
        for (int hh = 0; hh < 3; ++hh) {
            float e = __expf(leaky(als[s * 3 + hh] + aldv[hh]));
            wv[i * 3 + hh] = e;
            ss[hh] += e;
        }
    }
    #pragma unroll
    for (int hh = 0; hh < 3; ++hh) {
        #pragma unroll
        for (int off = 32; off; off >>= 1) ss[hh] += __shfl_xor(ss[hh], off, 64);
    }
    float inv[3];
    #pragma unroll
    for (int hh = 0; hh < 3; ++hh) inv[hh] = 1.f / (ss[hh] + 1e-16f);

    // pass C: lane -> (edge slot es, half2-channel lic); pair never straddles heads
    int es = lane >> 5, li = lane & 31;
    bool act = li < 27;
    int lic = act ? li : 26;
    int hh = lic / 9;
    float invh = pick(inv, hh);

    float accx = 0.f, accy = 0.f;
    int i = beg + es;
    for (; i + 14 < end; i += 16) {   // 8 edges per slot in flight
        int s0 = srcs[i],      s1 = srcs[i + 2],  s2 = srcs[i + 4],  s3 = srcs[i + 6];
        int s4 = srcs[i + 8],  s5 = srcs[i + 10], s6 = srcs[i + 12], s7 = srcs[i + 14];
        float w0 = wv[i * 3 + hh],        w1 = wv[(i + 2) * 3 + hh];
        float w2 = wv[(i + 4) * 3 + hh],  w3 = wv[(i + 6) * 3 + hh];
        float w4 = wv[(i + 8) * 3 + hh],  w5 = wv[(i + 10) * 3 + hh];
        float w6 = wv[(i + 12) * 3 + hh], w7 = wv[(i + 14) * 3 + hh];
        float2 v0 = __half22float2(hv[s0 * 27 + lic]), v1 = __half22float2(hv[s1 * 27 + lic]);
        float2 v2 = __half22float2(hv[s2 * 27 + lic]), v3 = __half22float2(hv[s3 * 27 + lic]);
        float2 v4 = __half22float2(hv[s4 * 27 + lic]), v5 = __half22float2(hv[s5 * 27 + lic]);
        float2 v6 = __half22float2(hv[s6 * 27 + lic]), v7 = __half22float2(hv[s7 * 27 + lic]);
        accx += v0.x * w0 + v1.x * w1 + v2.x * w2 + v3.x * w3
              + v4.x * w4 + v5.x * w5 + v6.x * w6 + v7.x * w7;
        accy += v0.y * w0 + v1.y * w1 + v2.y * w2 + v3.y * w3
              + v4.y * w4 + v5.y * w5 + v6.y * w6 + v7.y * w7;
    }
    for (; i < end; i += 2) {
        float w = wv[i * 3 + hh];
        float2 v = __half22float2(hv[srcs[i] * 27 + lic]);
        accx += v.x * w;
        accy += v.y * w;
    }
    accx += __shfl_xor(accx, 32, 64);   // both halves now hold full sums
    accy += __shfl_xor(accy, 32, 64);

    // epilogue: out2 pair -> relu -> W3 partials; reduce 27 lanes -> h3[4]
    float p0 = 0.f, p1 = 0.f, p2 = 0.f, p3 = 0.f;
    if (act) {
        float2 b = ((const float2*)bias)[lic];
        float r0 = fmaxf(accx * invh + b.x, 0.f);
        float r1 = fmaxf(accy * invh + b.y, 0.f);
        int c0 = 2 * lic, c1 = 2 * lic + 1;
        p0 = r0 * W3[c0 * 4 + 0] + r1 * W3[c1 * 4 + 0];
        p1 = r0 * W3[c0 * 4 + 1] + r1 * W3[c1 * 4 + 1];
        p2 = r0 * W3[c0 * 4 + 2] + r1 * W3[c1 * 4 + 2];
        p3 = r0 * W3[c0 * 4 + 3] + r1 * W3[c1 * 4 + 3];
    }
    #pragma unroll
    for (int off = 16; off; off >>= 1) {   // reduce within each 32-lane half
        p0 += __shfl_xor(p0, off, 64);
        p1 += __shfl_xor(p1, off, 64);
        p2 += __shfl_xor(p2, off, 64);
        p3 += __shfl_xor(p3, off, 64);
    }
    if (lane == 0) {
        float4 o; o.x = p0; o.y = p1; o.z = p2; o.w = p3;
        ((float4*)h3)[node] = o;
        als3[node] = p0 * as3[0] + p1 * as3[1] + p2 * as3[2] + p3 * as3[3];
        ald3[node] = p0 * ad3[0] + p1 * ad3[1] + p2 * ad3[2] + p3 * ad3[3];
    }
}

// ---------------------------------------------------------------------------
// Layer 3 aggregation fused with global max pool. 16 LANES PER NODE.
// Max-free softmax, exp recomputed in pass C (VALU idle; no wv round-trip).
// ---------------------------------------------------------------------------
__global__ void k_agg3pool(const int* __restrict__ rp, const int* __restrict__ srcs,
                           const float* __restrict__ h3, const float* __restrict__ als3,
                           const float* __restrict__ ald3, const float* __restrict__ b3,
                           const int* __restrict__ batch, unsigned* __restrict__ genc, int n) {
    int sub = threadIdx.x & 15;
    int node = blockIdx.x * (blockDim.x >> 4) + (threadIdx.x >> 4);
    if (node >= n) return;
    int beg = rp[node], end = rp[node + 1];
    float aldv = ald3[node];

    float ss = 0.f;
    for (int i = beg + sub; i < end; i += 16)
        ss += __expf(leaky(als3[srcs[i]] + aldv));
    #pragma unroll
    for (int off = 8; off; off >>= 1) ss += __shfl_xor(ss, off, 64);
    float inv = 1.f / (ss + 1e-16f);

    float ax = 0.f, ay = 0.f, az = 0.f, aw = 0.f;
    const float4* h4 = (const float4*)h3;
    for (int i = beg + sub; i < end; i += 16) {
        int s = srcs[i];
        float w = __expf(leaky(als3[s] + aldv));
        float4 v = h4[s];
        ax += v.x * w; ay += v.y * w; az += v.z * w; aw += v.w * w;
    }
    #pragma unroll
    for (int off = 8; off; off >>= 1) {
        ax += __shfl_xor(ax, off, 64);
        ay += __shfl_xor(ay, off, 64);
        az += __shfl_xor(az, off, 64);
        aw += __shfl_xor(aw, off, 64);
    }
    if (sub < 4) {
        float v = (sub == 0) ? ax : (sub == 1) ? ay : (sub == 2) ? az : aw;
        atomicMax(&genc[batch[node] * 4 + sub], f2mono(v * inv + b3[sub]));
    }
}

__global__ void k_final(const unsigned* __restrict__ genc, float* __restrict__ out) {
    int g = threadIdx.x;   // 256 threads, one per graph
    float v[4];
    #pragma unroll
    for (int c = 0; c < 4; ++c) v[c] = mono2f(genc[g * 4 + c]);
    float mx = fmaxf(fmaxf(v[0], v[1]), fmaxf(v[2], v[3]));
    float s = 0.f;
    #pragma unroll
    for (int c = 0; c < 4; ++c) s += expf(v[c] - mx);
    float l = mx + logf(s);
    #pragma unroll
    for (int c = 0; c < 4; ++c) out[g * 4 + c] = v[c] - l;
}

// ---------------------------------------------------------------------------
extern "C" void kernel_launch(void* const* d_in, const int* in_sizes, int n_in,
                              void* d_out, int out_size, void* d_ws, size_t ws_size,
                              hipStream_t stream) {
    const float* x     = (const float*)d_in[0];
    const int*   ei    = (const int*)d_in[1];     // [2, E] flat
    const int*   batch = (const int*)d_in[2];
    const float* W1    = (const float*)d_in[3];
    const float* as1   = (const float*)d_in[4];
    const float* ad1   = (const float*)d_in[5];
    const float* b1    = (const float*)d_in[6];
    const float* W2    = (const float*)d_in[7];
    const float* as2   = (const float*)d_in[8];
    const float* ad2   = (const float*)d_in[9];
    const float* b2    = (const float*)d_in[10];
    const float* W3    = (const float*)d_in[11];
    const float* as3   = (const float*)d_in[12];
    const float* ad3   = (const float*)d_in[13];
    const float* b3    = (const float*)d_in[14];
    float* out = (float*)d_out;

    const int* src = ei;
    const int* dst = ei + N_EDGES;

    char* base = (char*)d_ws;
    size_t off = 0;
    auto alloc = [&](size_t bytes) -> char* {
        char* p = base + off;
        off = (off + bytes + 255) & ~(size_t)255;
        return p;
    };
    int*      counts  = (int*)alloc((size_t)N_NODES * 4);
    int*      row_ptr = (int*)alloc((size_t)(N_NODES + 1) * 4);
    int*      srcs    = (int*)alloc((size_t)E_TOT * 4);
    int*      erank   = (int*)alloc((size_t)N_EDGES * 4);
    int*      bsum    = (int*)alloc(512 * 4);
    int*      boff    = (int*)alloc(512 * 4);
    float*    als     = (float*)alloc((size_t)N_NODES * 3 * 4);
    float*    ald     = (float*)alloc((size_t)N_NODES * 3 * 4);
    float*    als3    = (float*)alloc((size_t)N_NODES * 4);
    float*    ald3    = (float*)alloc((size_t)N_NODES * 4);
    float*    wv      = (float*)alloc((size_t)E_TOT * 3 * 4);   // unnormalized edge weights
    float*    aggx    = (float*)alloc((size_t)N_NODES * 27 * 4);
    __half2*  h2      = (__half2*)alloc((size_t)N_NODES * 27 * 4);  // 54 half = 27 half2
    float*    h3      = (float*)alloc((size_t)N_NODES * 4 * 4);
    unsigned* genc    = (unsigned*)alloc((size_t)N_GRAPHS * 4 * 4);
    if (off > ws_size) return;

    const int TB = 256;
    const int nb_n  = (N_NODES + TB - 1) / TB;      // 313
    const int nb_e  = (N_EDGES + TB - 1) / TB;      // 5000
    const int nb_w  = (N_NODES + 3) / 4;            // 4 node-waves per block
    const int nb_16 = (N_NODES + 15) / 16;          // 16 nodes per block (16 lanes each)

    // --- CSR build (rank trick: no scatter atomics) + layer-1 pre-pass ---
    k_init<<<nb_n, TB, 0, stream>>>(counts, genc);
    k_hist<<<nb_e, TB, 0, stream>>>(dst, counts, erank);
    k_scan_block<<<nb_n, SCAN_B, 0, stream>>>(counts, row_ptr, bsum, N_NODES);
    k_scan_tops<<<1, 512, 0, stream>>>(bsum, boff, nb_n);
    k_scan_add_pre1<<<nb_n, TB, 0, stream>>>(row_ptr, boff, srcs, x, W1, as1, ad1, als, ald, N_NODES);
    k_scatter<<<nb_e, TB, 0, stream>>>(src, dst, row_ptr, erank, srcs);

    // --- layer 1 (factorized: aggregate x, multiply by W1 inside lin2f) ---
    k_agg1x<<<nb_w, TB, 0, stream>>>(row_ptr, srcs, x, als, ald, wv, aggx, N_NODES);

    // --- layer 2 (h2 in fp16) ---
    k_lin2f<<<nb_n, TB, 0, stream>>>(aggx, W1, b1, W2, as2, ad2, h2, als, ald, N_NODES);
    // --- layer-2 agg + layer-3 linear fused ---
    k_agg2<<<nb_w, TB, 0, stream>>>(row_ptr, srcs, h2, als, ald, wv, b2,
                                    W3, as3, ad3, h3, als3, ald3, N_NODES);

    // --- layer 3 agg + pool ---
    k_agg3pool<<<nb_16, TB, 0, stream>>>(row_ptr, srcs, h3, als3, ald3, b3, batch, genc, N_NODES);
    k_final<<<1, N_GRAPHS, 0, stream>>>(genc, out);
}

// Round 12
// 442.218 us; speedup vs baseline: 2.7700x; 1.0828x over previous
//
#include <hip/hip_runtime.h>
#include <hip/hip_bf16.h>
#include <hip/hip_fp16.h>

#define N_NODES 80000
#define N_EDGES 1280000
#define E_TOT   (N_EDGES + N_NODES)   // + self loops
#define N_GRAPHS 256
#define NEG_SLOPE 0.2f

// leaky_relu(a) = max(a, 0.2*a)  (valid since 0<slope<1)
__device__ __forceinline__ float leaky(float a) { return fmaxf(a, NEG_SLOPE * a); }

// pick arr[h] with runtime h from a static-unrolled register array (no scratch)
template <int H>
__device__ __forceinline__ float pick(const float (&arr)[H], int h) {
    float r = arr[0];
    #pragma unroll
    for (int j = 1; j < H; ++j) r = (h == j) ? arr[j] : r;
    return r;
}

__device__ __forceinline__ unsigned f2mono(float f) {
    unsigned u = __float_as_uint(f);
    return u ^ ((u >> 31) ? 0xFFFFFFFFu : 0x80000000u);
}
__device__ __forceinline__ float mono2f(unsigned u) {
    u = (u & 0x80000000u) ? (u ^ 0x80000000u) : ~u;
    return __uint_as_float(u);
}

// ---------------------------------------------------------------------------
// Init: counts=1 (self-loop), init pool accumulators
// ---------------------------------------------------------------------------
__global__ void k_init(int* __restrict__ counts, unsigned* __restrict__ genc) {
    int i = blockIdx.x * blockDim.x + threadIdx.x;
    if (i < N_NODES) counts[i] = 1;
    if (i < N_GRAPHS * 4) genc[i] = f2mono(-1e9f);
}

// ---------------------------------------------------------------------------
// CSR build (by dst). hist also records each edge's within-node rank, so
// scatter needs NO atomics. Self-loop owns rank 0 (counts init = 1).
// ---------------------------------------------------------------------------
__global__ void k_hist(const int* __restrict__ dst, int* __restrict__ counts,
                       int* __restrict__ erank) {
    int i = blockIdx.x * blockDim.x + threadIdx.x;
    if (i >= N_EDGES) return;
    erank[i] = atomicAdd(&counts[dst[i]], 1);
}

#define SCAN_B 256
__global__ void k_scan_block(const int* __restrict__ counts, int* __restrict__ rp,
                             int* __restrict__ bsum, int n) {
    __shared__ int sa[SCAN_B], sb[SCAN_B];
    int tid = threadIdx.x;
    int gi = blockIdx.x * SCAN_B + tid;
    int v = (gi < n) ? counts[gi] : 0;
    sa[tid] = v;
    __syncthreads();
    int* cur = sa; int* nxt = sb;
    #pragma unroll
    for (int d = 1; d < SCAN_B; d <<= 1) {
        int t = cur[tid];
        if (tid >= d) t += cur[tid - d];
        nxt[tid] = t;
        __syncthreads();
        int* tmp = cur; cur = nxt; nxt = tmp;
    }
    if (gi < n) rp[gi] = cur[tid] - v;            // block-local exclusive
    if (tid == SCAN_B - 1) bsum[blockIdx.x] = cur[tid];
}

__global__ void k_scan_tops(const int* __restrict__ bsum, int* __restrict__ boff, int nb) {
    __shared__ int sa[512], sb[512];
    int tid = threadIdx.x;
    int v = (tid < nb) ? bsum[tid] : 0;
    sa[tid] = v;
    __syncthreads();
    int* cur = sa; int* nxt = sb;
    #pragma unroll
    for (int d = 1; d < 512; d <<= 1) {
        int t = cur[tid];
        if (tid >= d) t += cur[tid - d];
        nxt[tid] = t;
        __syncthreads();
        int* tmp = cur; cur = nxt; nxt = tmp;
    }
    if (tid < nb) boff[tid] = cur[tid] - v;
}

// scan finalize FUSED with (a) self-loop scatter into srcs, (b) layer-1
// pre-pass: als1/ald1 from x via projected 3x9 matrices.
__global__ void k_scan_add_pre1(int* __restrict__ rp, const int* __restrict__ boff,
                                int* __restrict__ srcs,
                                const float* __restrict__ x, const float* __restrict__ W1,
                                const float* __restrict__ as1, const float* __restrict__ ad1,
                                float* __restrict__ als, float* __restrict__ ald, int n) {
    __shared__ float ps[27], pd[27];
    int t = threadIdx.x;
    int gi = blockIdx.x * blockDim.x + t;
    if (gi < n) {
        int r = rp[gi] + boff[blockIdx.x];
        rp[gi] = r;
        srcs[r] = gi;                 // self-loop at rank 0
    }
    if (gi == 0) rp[n] = E_TOT;
    if (t < 27) {
        int h = t / 9, k = t % 9;
        float s = 0.f, d = 0.f;
        for (int c = 0; c < 45; ++c) {
            float w = W1[k * 135 + h * 45 + c];
            s += w * as1[h * 45 + c];
            d += w * ad1[h * 45 + c];
        }
        ps[t] = s; pd[t] = d;
    }
    __syncthreads();
    if (gi >= n) return;
    float xr[9];
    #pragma unroll
    for (int k = 0; k < 9; ++k) xr[k] = x[gi * 9 + k];
    #pragma unroll
    for (int h = 0; h < 3; ++h) {
        float s = 0.f, d = 0.f;
        #pragma unroll
        for (int k = 0; k < 9; ++k) { s += xr[k] * ps[h * 9 + k]; d += xr[k] * pd[h * 9 + k]; }
        als[gi * 3 + h] = s;
        ald[gi * 3 + h] = d;
    }
}

// atomic-free scatter: pos = rp[dst] + erank
__global__ void k_scatter(const int* __restrict__ src, const int* __restrict__ dst,
                          const int* __restrict__ rp, const int* __restrict__ erank,
                          int* __restrict__ srcs) {
    int i = blockIdx.x * blockDim.x + threadIdx.x;
    if (i >= N_EDGES) return;
    srcs[rp[dst[i]] + erank[i]] = src[i];
}

// ---------------------------------------------------------------------------
// Layer 1 aggregation over x (factorized), SINGLE PASS:
// weight w recomputed inline (exp is cheap); Sum_w accumulated in the same
// loop (9 lanes/head hold identical partials; designated lane read via shfl).
// Normalizer applied once after the reduction.
// ---------------------------------------------------------------------------
__global__ void k_agg1x(const int* __restrict__ rp, const int* __restrict__ srcs,
                        const float* __restrict__ x, const float* __restrict__ als,
                        const float* __restrict__ ald, float* __restrict__ aggx, int n) {
    int wid = threadIdx.x >> 6, lane = threadIdx.x & 63;
    int node = blockIdx.x * (blockDim.x >> 6) + wid;
    if (node >= n) return;
    int beg = rp[node], end = rp[node + 1];

    float aldv[3];
    #pragma unroll
    for (int h = 0; h < 3; ++h) aldv[h] = ald[node * 3 + h];

    // lane -> (edge slot es, channel lic=(hh,kk))
    int es = lane >> 5, li = lane & 31;
    int lic = li < 27 ? li : 26;     // clamp keeps loads in-bounds, no branch
    int hh = lic / 9;
    int kk = lic % 9;
    float aldh = pick(aldv, hh);

    float acc = 0.f, ssp = 0.f;
    int i = beg + es;
    for (; i + 14 < end; i += 16) {   // 8 edges per slot in flight
        int s0 = srcs[i],      s1 = srcs[i + 2],  s2 = srcs[i + 4],  s3 = srcs[i + 6];
        int s4 = srcs[i + 8],  s5 = srcs[i + 10], s6 = srcs[i + 12], s7 = srcs[i + 14];
        float a0 = als[s0 * 3 + hh], a1 = als[s1 * 3 + hh];
        float a2 = als[s2 * 3 + hh], a3 = als[s3 * 3 + hh];
        float a4 = als[s4 * 3 + hh], a5 = als[s5 * 3 + hh];
        float a6 = als[s6 * 3 + hh], a7 = als[s7 * 3 + hh];
        float x0 = x[s0 * 9 + kk], x1 = x[s1 * 9 + kk];
        float x2 = x[s2 * 9 + kk], x3 = x[s3 * 9 + kk];
        float x4 = x[s4 * 9 + kk], x5 = x[s5 * 9 + kk];
        float x6 = x[s6 * 9 + kk], x7 = x[s7 * 9 + kk];
        float w0 = __expf(leaky(a0 + aldh)), w1 = __expf(leaky(a1 + aldh));
        float w2 = __expf(leaky(a2 + aldh)), w3 = __expf(leaky(a3 + aldh));
        float w4 = __expf(leaky(a4 + aldh)), w5 = __expf(leaky(a5 + aldh));
        float w6 = __expf(leaky(a6 + aldh)), w7 = __expf(leaky(a7 + aldh));
        ssp += (w0 + w1 + w2 + w3) + (w4 + w5 + w6 + w7);
        acc += x0 * w0 + x1 * w1 + x2 * w2 + x3 * w3
             + x4 * w4 + x5 * w5 + x6 * w6 + x7 * w7;
    }
    for (; i < end; i += 2) {
        int s = srcs[i];
        float w = __expf(leaky(als[s * 3 + hh] + aldh));
        ssp += w;
        acc += x[s * 9 + kk] * w;
    }
    // Sum_w: designated lanes hh*9 (slot 0) and 32+hh*9 (slot 1)
    float sst = __shfl(ssp, hh * 9, 64) + __shfl(ssp, 32 + hh * 9, 64);
    float inv = 1.f / (sst + 1e-16f);
    acc += __shfl_xor(acc, 32, 64);
    if (lane < 27) aggx[node * 27 + lane] = acc * inv;
}

// ---------------------------------------------------------------------------
// Fused: out1 = aggx @ W1 + b1 -> ReLU -> h2 = out1 @ W2 ; als2/ald2 dots.
// h2 stored as FP16 (halves the layer-2 gather table: 17 -> 8.6 MB).
// ---------------------------------------------------------------------------
__global__ void k_lin2f(const float* __restrict__ aggx, const float* __restrict__ W1,
                        const float* __restrict__ b1, const float* __restrict__ W2,
                        const float* __restrict__ as2, const float* __restrict__ ad2,
                        __half2* __restrict__ h2, float* __restrict__ als,
                        float* __restrict__ ald, int n) {
    int node = blockIdx.x * blockDim.x + threadIdx.x;
    if (node >= n) return;
    float ax[27];
    #pragma unroll
    for (int j = 0; j < 27; ++j) ax[j] = aggx[node * 27 + j];
    float acc[54];
    #pragma unroll
    for (int c = 0; c < 54; ++c) acc[c] = 0.f;
    #pragma unroll
    for (int h = 0; h < 3; ++h) {          // must be unrolled: ax[] static idx
        #pragma unroll 1
        for (int c0 = 0; c0 < 45; ++c0) {
            int col = h * 45 + c0;
            float t = b1[col];
            #pragma unroll
            for (int k = 0; k < 9; ++k) t += ax[h * 9 + k] * W1[k * 135 + col];
            t = fmaxf(t, 0.f);             // ReLU between layers
            #pragma unroll
            for (int cc = 0; cc < 54; ++cc) acc[cc] += t * W2[col * 54 + cc];
        }
    }
    float as_[3] = {0.f, 0.f, 0.f}, ad_[3] = {0.f, 0.f, 0.f};
    #pragma unroll
    for (int c = 0; c < 54; ++c) {
        as_[c / 18] += acc[c] * as2[c];
        ad_[c / 18] += acc[c] * ad2[c];
    }
    #pragma unroll
    for (int j = 0; j < 27; ++j)
        h2[node * 27 + j] = __floats2half2_rn(acc[2 * j], acc[2 * j + 1]);
    #pragma unroll
    for (int h = 0; h < 3; ++h) { als[node * 3 + h] = as_[h]; ald[node * 3 + h] = ad_[h]; }
}

// ---------------------------------------------------------------------------
// Layer 2 aggregation (h2 in FP16), SINGLE PASS (inline exp + in-loop Sum_w),
// FUSED with layer-3 linear epilogue (out2 never materialized).
// ---------------------------------------------------------------------------
__global__ void k_agg2(const int* __restrict__ rp, const int* __restrict__ srcs,
                       const __half2* __restrict__ hv, const float* __restrict__ als,
                       const float* __restrict__ ald,
                       const float* __restrict__ bias, const float* __restrict__ W3,
                       const float* __restrict__ as3, const float* __restrict__ ad3,
                       float* __restrict__ h3, float* __restrict__ als3,
                       float* __restrict__ ald3, int n) {
    int wid = threadIdx.x >> 6, lane = threadIdx.x & 63;
    int node = blockIdx.x * (blockDim.x >> 6) + wid;
    if (node >= n) return;
    int beg = rp[node], end = rp[node + 1];

    float aldv[3];
    #pragma unroll
    for (int hh = 0; hh < 3; ++hh) aldv[hh] = ald[node * 3 + hh];

    // lane -> (edge slot es, half2-channel lic); pair never straddles heads
    int es = lane >> 5, li = lane & 31;
    bool act = li < 27;
    int lic = act ? li : 26;
    int hh = lic / 9;
    float aldh = pick(aldv, hh);

    float accx = 0.f, accy = 0.f, ssp = 0.f;
    int i = beg + es;
    for (; i + 14 < end; i += 16) {   // 8 edges per slot in flight
        int s0 = srcs[i],      s1 = srcs[i + 2],  s2 = srcs[i + 4],  s3 = srcs[i + 6];
        int s4 = srcs[i + 8],  s5 = srcs[i + 10], s6 = srcs[i + 12], s7 = srcs[i + 14];
        float a0 = als[s0 * 3 + hh], a1 = als[s1 * 3 + hh];
        float a2 = als[s2 * 3 + hh], a3 = als[s3 * 3 + hh];
        float a4 = als[s4 * 3 + hh], a5 = als[s5 * 3 + hh];
        float a6 = als[s6 * 3 + hh], a7 = als[s7 * 3 + hh];
        float2 v0 = __half22float2(hv[s0 * 27 + lic]), v1 = __half22float2(hv[s1 * 27 + lic]);
        float2 v2 = __half22float2(hv[s2 * 27 + lic]), v3 = __half22float2(hv[s3 * 27 + lic]);
        float2 v4 = __half22float2(hv[s4 * 27 + lic]), v5 = __half22float2(hv[s5 * 27 + lic]);
        float2 v6 = __half22float2(hv[s6 * 27 + lic]), v7 = __half22float2(hv[s7 * 27 + lic]);
        float w0 = __expf(leaky(a0 + aldh)), w1 = __expf(leaky(a1 + aldh));
        float w2 = __expf(leaky(a2 + aldh)), w3 = __expf(leaky(a3 + aldh));
        float w4 = __expf(leaky(a4 + aldh)), w5 = __expf(leaky(a5 + aldh));
        float w6 = __expf(leaky(a6 + aldh)), w7 = __expf(leaky(a7 + aldh));
        ssp += (w0 + w1 + w2 + w3) + (w4 + w5 + w6 + w7);
        accx += v0.x * w0 + v1.x * w1 + v2.x * w2 + v3.x * w3
              + v4.x * w4 + v5.x * w5 + v6.x * w6 + v7.x * w7;
        accy += v0.y * w0 + v1.y * w1 + v2.y * w2 + v3.y * w3
              + v4.y * w4 + v5.y * w5 + v6.y * w6 + v7.y * w7;
    }
    for (; i < end; i += 2) {
        int s = srcs[i];
        float w = __expf(leaky(als[s * 3 + hh] + aldh));
        float2 v = __half22float2(hv[s * 27 + lic]);
        ssp += w;
        accx += v.x * w;
        accy += v.y * w;
    }
    float sst = __shfl(ssp, hh * 9, 64) + __shfl(ssp, 32 + hh * 9, 64);
    float invh = 1.f / (sst + 1e-16f);
    accx += __shfl_xor(accx, 32, 64);   // both halves now hold full sums
    accy += __shfl_xor(accy, 32, 64);

    // epilogue: out2 pair -> relu -> W3 partials; reduce 27 lanes -> h3[4]
    float p0 = 0.f, p1 = 0.f, p2 = 0.f, p3 = 0.f;
    if (act) {
        float2 b = ((const float2*)bias)[lic];
        float r0 = fmaxf(accx * invh + b.x, 0.f);
        float r1 = fmaxf(accy * invh + b.y, 0.f);
        int c0 = 2 * lic, c1 = 2 * lic + 1;
        p0 = r0 * W3[c0 * 4 + 0] + r1 * W3[c1 * 4 + 0];
        p1 = r0 * W3[c0 * 4 + 1] + r1 * W3[c1 * 4 + 1];
        p2 = r0 * W3[c0 * 4 + 2] + r1 * W3[c1 * 4 + 2];
        p3 = r0 * W3[c0 * 4 + 3] + r1 * W3[c1 * 4 + 3];
    }
    #pragma unroll
    for (int off = 16; off; off >>= 1) {   // reduce within each 32-lane half
        p0 += __shfl_xor(p0, off, 64);
        p1 += __shfl_xor(p1, off, 64);
        p2 += __shfl_xor(p2, off, 64);
        p3 += __shfl_xor(p3, off, 64);
    }
    if (lane == 0) {
        float4 o; o.x = p0; o.y = p1; o.z = p2; o.w = p3;
        ((float4*)h3)[node] = o;
        als3[node] = p0 * as3[0] + p1 * as3[1] + p2 * as3[2] + p3 * as3[3];
        ald3[node] = p0 * ad3[0] + p1 * ad3[1] + p2 * ad3[2] + p3 * ad3[3];
    }
}

// ---------------------------------------------------------------------------
// Layer 3 aggregation fused with global max pool. 16 LANES PER NODE.
// SINGLE PASS: Sum_w and weighted sum in the same loop; scale after reduce.
// ---------------------------------------------------------------------------
__global__ void k_agg3pool(const int* __restrict__ rp, const int* __restrict__ srcs,
                           const float* __restrict__ h3, const float* __restrict__ als3,
                           const float* __restrict__ ald3, const float* __restrict__ b3,
                           const int* __restrict__ batch, unsigned* __restrict__ genc, int n) {
    int sub = threadIdx.x & 15;
    int node = blockIdx.x * (blockDim.x >> 4) + (threadIdx.x >> 4);
    if (node >= n) return;
    int beg = rp[node], end = rp[node + 1];
    float aldv = ald3[node];

    float ss = 0.f, ax = 0.f, ay = 0.f, az = 0.f, aw = 0.f;
    const float4* h4 = (const float4*)h3;
    for (int i = beg + sub; i < end; i += 16) {
        int s = srcs[i];
        float w = __expf(leaky(als3[s] + aldv));
        float4 v = h4[s];
        ss += w;
        ax += v.x * w; ay += v.y * w; az += v.z * w; aw += v.w * w;
    }
    #pragma unroll
    for (int off = 8; off; off >>= 1) {
        ss += __shfl_xor(ss, off, 64);
        ax += __shfl_xor(ax, off, 64);
        ay += __shfl_xor(ay, off, 64);
        az += __shfl_xor(az, off, 64);
        aw += __shfl_xor(aw, off, 64);
    }
    if (sub < 4) {
        float inv = 1.f / (ss + 1e-16f);
        float v = (sub == 0) ? ax : (sub == 1) ? ay : (sub == 2) ? az : aw;
        atomicMax(&genc[batch[node] * 4 + sub], f2mono(v * inv + b3[sub]));
    }
}

__global__ void k_final(const unsigned* __restrict__ genc, float* __restrict__ out) {
    int g = threadIdx.x;   // 256 threads, one per graph
    float v[4];
    #pragma unroll
    for (int c = 0; c < 4; ++c) v[c] = mono2f(genc[g * 4 + c]);
    float mx = fmaxf(fmaxf(v[0], v[1]), fmaxf(v[2], v[3]));
    float s = 0.f;
    #pragma unroll
    for (int c = 0; c < 4; ++c) s += expf(v[c] - mx);
    float l = mx + logf(s);
    #pragma unroll
    for (int c = 0; c < 4; ++c) out[g * 4 + c] = v[c] - l;
}

// ---------------------------------------------------------------------------
extern "C" void kernel_launch(void* const* d_in, const int* in_sizes, int n_in,
                              void* d_out, int out_size, void* d_ws, size_t ws_size,
                              hipStream_t stream) {
    const float* x     = (const float*)d_in[0];
    const int*   ei    = (const int*)d_in[1];     // [2, E] flat
    const int*   batch = (const int*)d_in[2];
    const float* W1    = (const float*)d_in[3];
    const float* as1   = (const float*)d_in[4];
    const float* ad1   = (const float*)d_in[5];
    const float* b1    = (const float*)d_in[6];
    const float* W2    = (const float*)d_in[7];
    const float* as2   = (const float*)d_in[8];
    const float* ad2   = (const float*)d_in[9];
    const float* b2    = (const float*)d_in[10];
    const float* W3    = (const float*)d_in[11];
    const float* as3   = (const float*)d_in[12];
    const float* ad3   = (const float*)d_in[13];
    const float* b3    = (const float*)d_in[14];
    float* out = (float*)d_out;

    const int* src = ei;
    const int* dst = ei + N_EDGES;

    char* base = (char*)d_ws;
    size_t off = 0;
    auto alloc = [&](size_t bytes) -> char* {
        char* p = base + off;
        off = (off + bytes + 255) & ~(size_t)255;
        return p;
    };
    int*      counts  = (int*)alloc((size_t)N_NODES * 4);
    int*      row_ptr = (int*)alloc((size_t)(N_NODES + 1) * 4);
    int*      srcs    = (int*)alloc((size_t)E_TOT * 4);
    int*      erank   = (int*)alloc((size_t)N_EDGES * 4);
    int*      bsum    = (int*)alloc(512 * 4);
    int*      boff    = (int*)alloc(512 * 4);
    float*    als     = (float*)alloc((size_t)N_NODES * 3 * 4);
    float*    ald     = (float*)alloc((size_t)N_NODES * 3 * 4);
    float*    als3    = (float*)alloc((size_t)N_NODES * 4);
    float*    ald3    = (float*)alloc((size_t)N_NODES * 4);
    float*    aggx    = (float*)alloc((size_t)N_NODES * 27 * 4);
    __half2*  h2      = (__half2*)alloc((size_t)N_NODES * 27 * 4);  // 54 half = 27 half2
    float*    h3      = (float*)alloc((size_t)N_NODES * 4 * 4);
    unsigned* genc    = (unsigned*)alloc((size_t)N_GRAPHS * 4 * 4);
    if (off > ws_size) return;

    const int TB = 256;
    const int nb_n  = (N_NODES + TB - 1) / TB;      // 313
    const int nb_e  = (N_EDGES + TB - 1) / TB;      // 5000
    const int nb_w  = (N_NODES + 3) / 4;            // 4 node-waves per block
    const int nb_16 = (N_NODES + 15) / 16;          // 16 nodes per block (16 lanes each)

    // --- CSR build (rank trick: no scatter atomics) + layer-1 pre-pass ---
    k_init<<<nb_n, TB, 0, stream>>>(counts, genc);
    k_hist<<<nb_e, TB, 0, stream>>>(dst, counts, erank);
    k_scan_block<<<nb_n, SCAN_B, 0, stream>>>(counts, row_ptr, bsum, N_NODES);
    k_scan_tops<<<1, 512, 0, stream>>>(bsum, boff, nb_n);
    k_scan_add_pre1<<<nb_n, TB, 0, stream>>>(row_ptr, boff, srcs, x, W1, as1, ad1, als, ald, N_NODES);
    k_scatter<<<nb_e, TB, 0, stream>>>(src, dst, row_ptr, erank, srcs);

    // --- layer 1 (factorized: aggregate x, multiply by W1 inside lin2f) ---
    k_agg1x<<<nb_w, TB, 0, stream>>>(row_ptr, srcs, x, als, ald, aggx, N_NODES);

    // --- layer 2 (h2 in fp16) ---
    k_lin2f<<<nb_n, TB, 0, stream>>>(aggx, W1, b1, W2, as2, ad2, h2, als, ald, N_NODES);
    // --- layer-2 agg + layer-3 linear fused ---
    k_agg2<<<nb_w, TB, 0, stream>>>(row_ptr, srcs, h2, als, ald, b2,
                                    W3, as3, ad3, h3, als3, ald3, N_NODES);

    // --- layer 3 agg + pool ---
    k_agg3pool<<<nb_16, TB, 0, stream>>>(row_ptr, srcs, h3, als3, ald3, b3, batch, genc, N_NODES);
    k_final<<<1, N_GRAPHS, 0, stream>>>(genc, out);
}